// Round 1
// 656.766 us; speedup vs baseline: 1.0291x; 1.0291x over previous
//
#include <hip/hip_runtime.h>
#include <cstddef>
#include <cstdint>

#define NB   8
#define LQ   1024
#define CH   512
#define HHE  8
#define HDD  64
#define PPM  16
#define LP   1040     // L + P
#define HID  2048

typedef unsigned short ushort_t;
typedef __attribute__((ext_vector_type(8))) short short8;
typedef __attribute__((ext_vector_type(4))) float floatx4;

// ---- workspace layout (float element offsets) ----
static const size_t O_QB   = 0;          // Qb bf16   (2,097,152 fl)
static const size_t O_KB   = 2097152;    // Kb bf16   (2,129,920 fl)
static const size_t O_VB   = 4227072;    // Vb bf16   (2,129,920 fl)
static const size_t O_VT   = 6356992;    // VT bf16   (2,129,920 fl)
static const size_t O_AOB  = 8486912;    // aob bf16  (2,097,152 fl)
static const size_t O_AF   = 10584064;   // abf/fbf fp32 (4,194,304 fl)
// hraw bf16 overlays floats [0 .. 16,777,216) -- all of the above are dead then
static const size_t O_X1B  = 16777216;   // x1b padded bf16 (2,101,248 fl)
static const size_t O_HPAD = 18878464;   // hpad bf16 (8,404,992 fl)
static const size_t O_W1   = 27283456;   // w1 bf16   (3,145,728 fl)
static const size_t O_W2   = 30429184;   // w2 bf16   (1,572,864 fl)
static const size_t O_WO   = 32002048;   // wo bf16   (131,072 fl)
// total 32,133,120 floats = 128.5 MB

__device__ __forceinline__ ushort_t f2bf(float f) {
  uint32_t u = __float_as_uint(f);
  u += 0x7FFFu + ((u >> 16) & 1u);
  return (ushort_t)(u >> 16);
}
__device__ __forceinline__ float bf2f(ushort_t h) {
  return __uint_as_float(((uint32_t)h) << 16);
}

__device__ __forceinline__ void async16(ushort_t* lds, const ushort_t* g) {
  __builtin_amdgcn_global_load_lds(
      (const __attribute__((address_space(1))) void*)g,
      (__attribute__((address_space(3))) void*)lds, 16, 0, 0);
}

// ---------------------------------------------------------------------------
// weight pack to bf16 [oc][k], k = dl*IC + ic; src[oc*K + ic*KD + dl]
// ---------------------------------------------------------------------------
__global__ __launch_bounds__(256) void pack_bf16_kernel(
    const float* __restrict__ src, ushort_t* __restrict__ dst,
    int K, int KD, int icShift)
{
  const int oc = blockIdx.x;
  const int icMask = (1 << icShift) - 1;
  for (int k = threadIdx.x; k < K; k += 256) {
    int ic = k & icMask, dl = k >> icShift;
    dst[(size_t)oc * K + k] = f2bf(src[(size_t)oc * K + ic * KD + dl]);
  }
}

// ---------------------------------------------------------------------------
// Generic bf16 MFMA GEMM, 128x128 tile, BK=32, global_load_lds staging.
// ---------------------------------------------------------------------------
template<int EPI>
__global__ __launch_bounds__(256, 2) void mfma_gemm(
    const ushort_t* __restrict__ Ab, const ushort_t* __restrict__ Bb,
    int K, int BS, int P, int NOUT,
    const float* __restrict__ bias, const float* __restrict__ res,
    float* __restrict__ outf, ushort_t* __restrict__ outh)
{
  __shared__ ushort_t As[128 * 32];
  __shared__ ushort_t Bs[128 * 32];
  const int t = threadIdx.x;
  const int w = t >> 6, l = t & 63;
  const int m0 = blockIdx.x * 128, n0 = blockIdx.y * 128;

  const int sub = l >> 2;
  const int kc8 = (l & 3) * 8;
  const ushort_t* aptr[2];
  const ushort_t* bptr[2];
  #pragma unroll
  for (int c = 0; c < 2; ++c) {
    int arow = m0 + w * 32 + c * 16 + sub;
    aptr[c] = Ab + (size_t)(arow >> 10) * BS + (size_t)(arow & 1023) * P + kc8;
    int brow = n0 + w * 32 + c * 16 + sub;
    bptr[c] = Bb + (size_t)brow * K + kc8;
  }

  const int wm = w >> 1, wn = w & 1;
  const int lm = l & 15, q = l >> 4;
  floatx4 acc[4][4];
  #pragma unroll
  for (int i = 0; i < 4; ++i)
    #pragma unroll
    for (int j = 0; j < 4; ++j)
      acc[i][j] = (floatx4){0.f, 0.f, 0.f, 0.f};

  const int kIters = K >> 5;
  for (int kt = 0; kt < kIters; ++kt) {
    __syncthreads();
    async16(&As[w * 1024 +   0], aptr[0]);
    async16(&As[w * 1024 + 512], aptr[1]);
    async16(&Bs[w * 1024 +   0], bptr[0]);
    async16(&Bs[w * 1024 + 512], bptr[1]);
    aptr[0] += 32; aptr[1] += 32; bptr[0] += 32; bptr[1] += 32;
    __syncthreads();
    short8 af[4], bf[4];
    #pragma unroll
    for (int i = 0; i < 4; ++i)
      af[i] = *(const short8*)&As[(wm * 64 + i * 16 + lm) * 32 + q * 8];
    #pragma unroll
    for (int i = 0; i < 4; ++i)
      bf[i] = *(const short8*)&Bs[(wn * 64 + i * 16 + lm) * 32 + q * 8];
    #pragma unroll
    for (int i = 0; i < 4; ++i)
      #pragma unroll
      for (int j = 0; j < 4; ++j)
        acc[i][j] = __builtin_amdgcn_mfma_f32_16x16x32_bf16(af[i], bf[j], acc[i][j], 0, 0, 0);
  }

  #pragma unroll
  for (int i = 0; i < 4; ++i) {
    #pragma unroll
    for (int j = 0; j < 4; ++j) {
      const int mbase = m0 + wm * 64 + i * 16 + q * 4;
      const int n = n0 + wn * 64 + j * 16 + lm;
      #pragma unroll
      for (int r = 0; r < 4; ++r) {
        const int m = mbase + r;
        float v = acc[i][j][r];
        if (EPI == 0) {
          outh[(size_t)m * NOUT + n] = f2bf(v);
        } else if (EPI == 1) {
          outf[(size_t)m * NOUT + n] = v + bias[n];
        } else {
          outf[(size_t)m * NOUT + n] = v + bias[n] + res[(size_t)m * NOUT + n];
        }
      }
    }
  }
}

// ---------------------------------------------------------------------------
// QKV projection via MFMA. grid (128, 3): blockIdx.x = 64-token tile,
// blockIdx.y = matrix (0=Q,1=K,2=V). W (64x64) staged to LDS in fragment
// order; A-fragments read from global fp32, converted in-register.
// Per head h: q[t, h*64+d] = sum_e x[t, h*64+e] * W[d][e].
// ---------------------------------------------------------------------------
__global__ __launch_bounds__(256) void qkv_mfma(
    const float* __restrict__ x,
    const float* __restrict__ Wq, const float* __restrict__ Wk, const float* __restrict__ Wv,
    ushort_t* __restrict__ qo, ushort_t* __restrict__ ko, ushort_t* __restrict__ vo)
{
  __shared__ ushort_t Ws[8 * 512];   // frag (nt,s): [((nt*2+s)*64 + lane)*8 + j]
  const int mat = blockIdx.y;
  const float* __restrict__ W = (mat == 0) ? Wq : (mat == 1) ? Wk : Wv;
  const int t = threadIdx.x;

  // stage W: element (oc, ic) -> frag slot (nt=oc>>4, s=ic>>5), lane quad*16+lm
  for (int e = t; e < 4096; e += 256) {
    const int oc = e >> 6, ic = e & 63;
    const int nt = oc >> 4, lmm = oc & 15, s = ic >> 5, qd = (ic >> 3) & 3, j = ic & 7;
    Ws[(((nt * 2 + s) * 4 + qd) * 16 + lmm) * 8 + j] = f2bf(W[e]);
  }

  const int w = t >> 6, l = t & 63;
  const int lm = l & 15, quad = l >> 4;
  const int tok0 = blockIdx.x * 64 + w * 16;

  // A-fragments: token row = tok0+lm, k = h*64 + s*32 + quad*8 .. +8
  short8 af[16];
  {
    const float* xrow = x + (size_t)(tok0 + lm) * CH + quad * 8;
    #pragma unroll
    for (int h = 0; h < 8; ++h) {
      #pragma unroll
      for (int s = 0; s < 2; ++s) {
        const float4 a = *(const float4*)(xrow + h * 64 + s * 32);
        const float4 b = *(const float4*)(xrow + h * 64 + s * 32 + 4);
        short8 f;
        f[0] = (short)f2bf(a.x); f[1] = (short)f2bf(a.y);
        f[2] = (short)f2bf(a.z); f[3] = (short)f2bf(a.w);
        f[4] = (short)f2bf(b.x); f[5] = (short)f2bf(b.y);
        f[6] = (short)f2bf(b.z); f[7] = (short)f2bf(b.w);
        af[h * 2 + s] = f;
      }
    }
  }
  __syncthreads();

  short8 bfr[8];
  #pragma unroll
  for (int nt = 0; nt < 4; ++nt)
    #pragma unroll
    for (int s = 0; s < 2; ++s)
      bfr[nt * 2 + s] = *(const short8*)&Ws[((nt * 2 + s) * 64 + l) * 8];

  const int n = tok0 >> 10, lpos = tok0 & 1023;
  ushort_t* outp;
  size_t base;
  if (mat == 0) { base = ((size_t)n * LQ + lpos) * CH; outp = qo; }
  else          { base = ((size_t)n * LP + lpos) * CH; outp = (mat == 1) ? ko : vo; }

  #pragma unroll
  for (int h = 0; h < 8; ++h) {
    floatx4 acc[4];
    #pragma unroll
    for (int nt = 0; nt < 4; ++nt) acc[nt] = (floatx4){0.f, 0.f, 0.f, 0.f};
    #pragma unroll
    for (int nt = 0; nt < 4; ++nt)
      #pragma unroll
      for (int s = 0; s < 2; ++s)
        acc[nt] = __builtin_amdgcn_mfma_f32_16x16x32_bf16(
            af[h * 2 + s], bfr[nt * 2 + s], acc[nt], 0, 0, 0);
    // C/D: col = lane&15 (d within tile), row = quad*4 + r (token)
    #pragma unroll
    for (int nt = 0; nt < 4; ++nt)
      #pragma unroll
      for (int r = 0; r < 4; ++r)
        outp[base + (size_t)(quad * 4 + r) * CH + h * 64 + nt * 16 + lm] =
            f2bf(acc[nt][r]);
  }
}

__global__ __launch_bounds__(256) void persist_kernel(
    const float* __restrict__ pk, const float* __restrict__ pv,
    ushort_t* __restrict__ ko, ushort_t* __restrict__ vo)
{
  const int t = blockIdx.x * 256 + threadIdx.x;
  const int n = t >> 13, p = (t >> 9) & 15, c = t & 511, d = c & 63;
  const size_t o = ((size_t)n * LP + LQ + p) * CH + c;
  ko[o] = f2bf(pk[p * 64 + d]);
  vo[o] = f2bf(pv[p * 64 + d]);
}

// ---------------------------------------------------------------------------
// V transpose: Vb [n][k(1040)][512] -> VT [n][d(512)][1040]
// ---------------------------------------------------------------------------
__global__ __launch_bounds__(256) void vtrans_kernel(
    const ushort_t* __restrict__ Vb, ushort_t* __restrict__ VT)
{
  __shared__ ushort_t Ls[16 * 520];
  const int n = blockIdx.y, k0 = blockIdx.x * 16;
  const int t = threadIdx.x;
  const int r = t >> 4;
  {
    const ushort_t* src = Vb + ((size_t)(n * LP + k0 + r)) * 512 + (t & 15) * 8;
    ushort_t* dst = &Ls[r * 520 + (t & 15) * 8];
    #pragma unroll
    for (int it = 0; it < 4; ++it)
      *(short8*)(dst + it * 128) = *(const short8*)(src + it * 128);
  }
  __syncthreads();
  #pragma unroll
  for (int rep = 0; rep < 2; ++rep) {
    const int d = t + rep * 256;
    short8 v0, v1;
    #pragma unroll
    for (int j = 0; j < 8; ++j) {
      v0[j] = (short)Ls[j * 520 + d];
      v1[j] = (short)Ls[(8 + j) * 520 + d];
    }
    ushort_t* dst = VT + ((size_t)(n * 512 + d)) * LP + k0;
    *(short8*)(dst)     = v0;
    *(short8*)(dst + 8) = v1;
  }
}

// ---------------------------------------------------------------------------
// MFMA flash attention with talking heads + ALiBi.
// v2: T14 async-STAGE split — K (pass 1) and K+V (pass 2) are prefetched
// one 16-key step ahead into registers; the reg->LDS write happens after
// the barrier. Global (L2/L3-hit) latency hides under MFMA+softmax VALU
// instead of being serially exposed at every step's staging point.
// Math order is identical to v1.
// ---------------------------------------------------------------------------
__global__ __launch_bounds__(256, 2) void attn_mfma(
    const ushort_t* __restrict__ Qb, const ushort_t* __restrict__ Kb,
    const ushort_t* __restrict__ VT,
    const float* __restrict__ thpre, const float* __restrict__ thpost,
    ushort_t* __restrict__ aob)
{
  __shared__ ushort_t Ks[16 * 520];     // K tile [key][d], row pad 8
  __shared__ ushort_t Vt[512 * 40];     // V^T tile [d][k-pair 32], row pad 8
  __shared__ float   Ps[8 * 16 * 36];   // P [g][q][k-pair 32], row pad 4
  const int n = blockIdx.y, q0 = blockIdx.x * 16;
  const int t = threadIdx.x;
  const int w = t >> 6, l = t & 63;
  const int lm = l & 15, quad = l >> 4;
  const float invs = 0.044194173824159216f;  // 1/sqrt(512)

  short8 qf[16];
  {
    const ushort_t* qrow = Qb + ((size_t)(n * LQ + q0 + lm)) * 512 + quad * 8;
    #pragma unroll
    for (int h = 0; h < 8; ++h) {
      qf[h * 2 + 0] = *(const short8*)(qrow + h * 64);
      qf[h * 2 + 1] = *(const short8*)(qrow + h * 64 + 32);
    }
  }
  float tps[2][8], psl[2], tpo[2][8];
  #pragma unroll
  for (int gg = 0; gg < 2; ++gg) {
    const int g = w * 2 + gg;
    float ps = 0.f;
    #pragma unroll
    for (int h = 0; h < 8; ++h) {
      float tv = thpre[g * 8 + h] * invs;
      tps[gg][h] = tv;
      ps += tv * (1.0f / (float)(2 << h));   // slope_h = 2^-(h+1)
      tpo[gg][h] = thpost[g * 8 + h];
    }
    psl[gg] = ps;
  }

  float m_[2][4], z_[2][4], zi[2][4];
  #pragma unroll
  for (int gg = 0; gg < 2; ++gg)
    #pragma unroll
    for (int r = 0; r < 4; ++r) { m_[gg][r] = -1e30f; z_[gg][r] = 0.f; }

  floatx4 o_[2][4];
  #pragma unroll
  for (int gg = 0; gg < 2; ++gg)
    #pragma unroll
    for (int ch = 0; ch < 4; ++ch) o_[gg][ch] = (floatx4){0.f, 0.f, 0.f, 0.f};

  // ---- staging state ----
  const ushort_t* ksrc = Kb + ((size_t)(n * LP + (t >> 4))) * 512 + (t & 15) * 8;
  ushort_t* kdst = &Ks[(t >> 4) * 520 + (t & 15) * 8];
  const ushort_t* ksrc2;              // pass-2 K source (reset to k0=0)
  const ushort_t* vsA;                // V^T source, dim t
  const ushort_t* vsB;                // V^T source, dim t+256
  short8 kA[4], kB[4], vA[4], vB[4];
  const ushort_t* kbase = &Ks[lm * 520 + quad * 8];

  auto loadK = [&](short8 (&r)[4], const ushort_t* src) {
    #pragma unroll
    for (int it = 0; it < 4; ++it) r[it] = *(const short8*)(src + it * 128);
  };
  auto storeK = [&](short8 (&r)[4]) {
    #pragma unroll
    for (int it = 0; it < 4; ++it) *(short8*)(kdst + it * 128) = r[it];
  };
  auto loadV = [&](short8 (&r)[4]) {
    r[0] = *(const short8*)(vsA);  r[1] = *(const short8*)(vsA + 8);
    r[2] = *(const short8*)(vsB);  r[3] = *(const short8*)(vsB + 8);
    vsA += 16; vsB += 16;
  };
  auto storeV = [&](short8 (&r)[4], int sub) {
    ushort_t* d0 = &Vt[(size_t)t * 40 + sub * 16];
    ushort_t* d1 = &Vt[(size_t)(t + 256) * 40 + sub * 16];
    *(short8*)(d0)     = r[0]; *(short8*)(d0 + 8) = r[1];
    *(short8*)(d1)     = r[2]; *(short8*)(d1 + 8) = r[3];
  };

  auto qkt = [&](floatx4 (&ef)[8]) {
    #pragma unroll
    for (int h = 0; h < 8; ++h) {
      floatx4 e = (floatx4){0.f, 0.f, 0.f, 0.f};
      short8 b0 = *(const short8*)(kbase + h * 64);
      short8 b1 = *(const short8*)(kbase + h * 64 + 32);
      e = __builtin_amdgcn_mfma_f32_16x16x32_bf16(qf[h * 2 + 0], b0, e, 0, 0, 0);
      e = __builtin_amdgcn_mfma_f32_16x16x32_bf16(qf[h * 2 + 1], b1, e, 0, 0, 0);
      ef[h] = e;
    }
  };

  auto p1_compute = [&](int step) {
    floatx4 ef[8];
    qkt(ef);
    const int k0 = step * 16;
    const bool alibi = (step < 64);
    #pragma unroll
    for (int r = 0; r < 4; ++r) {
      const float dist = fabsf((float)(q0 + quad * 4 + r - (k0 + lm)));
      #pragma unroll
      for (int gg = 0; gg < 2; ++gg) {
        float s = tps[gg][0] * ef[0][r];
        #pragma unroll
        for (int h = 1; h < 8; ++h) s += tps[gg][h] * ef[h][r];
        if (alibi) s -= dist * psl[gg];
        const float mo = m_[gg][r];
        const float mn = fmaxf(mo, s);
        z_[gg][r] = z_[gg][r] * __expf(mo - mn) + __expf(s - mn);
        m_[gg][r] = mn;
      }
    }
  };

  auto p2_compute = [&](int step, int sub) {
    floatx4 ef[8];
    qkt(ef);
    const int k0 = step * 16;
    const bool alibi = (step < 64);
    #pragma unroll
    for (int r = 0; r < 4; ++r) {
      const float dist = fabsf((float)(q0 + quad * 4 + r - (k0 + lm)));
      #pragma unroll
      for (int gg = 0; gg < 2; ++gg) {
        float s = tps[gg][0] * ef[0][r];
        #pragma unroll
        for (int h = 1; h < 8; ++h) s += tps[gg][h] * ef[h][r];
        if (alibi) s -= dist * psl[gg];
        const float p = __expf(s - m_[gg][r]) * zi[gg][r];
        Ps[((w * 2 + gg) * 16 + quad * 4 + r) * 36 + sub * 16 + lm] = p;
        if (step == 64)
          Ps[((w * 2 + gg) * 16 + quad * 4 + r) * 36 + 16 + lm] = 0.f;
      }
    }
  };

  auto mix_av = [&]() {
    float pm[2][8];
    #pragma unroll
    for (int gg = 0; gg < 2; ++gg)
      #pragma unroll
      for (int j = 0; j < 8; ++j) pm[gg][j] = 0.f;
    #pragma unroll
    for (int g = 0; g < 8; ++g) {
      const float4 pa = *(const float4*)&Ps[(g * 16 + lm) * 36 + quad * 8];
      const float4 pb = *(const float4*)&Ps[(g * 16 + lm) * 36 + quad * 8 + 4];
      #pragma unroll
      for (int gg = 0; gg < 2; ++gg) {
        const float tw = tpo[gg][g];
        pm[gg][0] += tw * pa.x; pm[gg][1] += tw * pa.y;
        pm[gg][2] += tw * pa.z; pm[gg][3] += tw * pa.w;
        pm[gg][4] += tw * pb.x; pm[gg][5] += tw * pb.y;
        pm[gg][6] += tw * pb.z; pm[gg][7] += tw * pb.w;
      }
    }
    short8 pk[2];
    #pragma unroll
    for (int gg = 0; gg < 2; ++gg)
      #pragma unroll
      for (int j = 0; j < 8; ++j) pk[gg][j] = (short)f2bf(pm[gg][j]);
    #pragma unroll
    for (int gg = 0; gg < 2; ++gg) {
      #pragma unroll
      for (int ch = 0; ch < 4; ++ch) {
        const int d = (w * 2 + gg) * 64 + ch * 16 + lm;
        const short8 vf = *(const short8*)&Vt[d * 40 + quad * 8];
        o_[gg][ch] = __builtin_amdgcn_mfma_f32_16x16x32_bf16(pk[gg], vf, o_[gg][ch], 0, 0, 0);
      }
    }
  };

  auto p2_step = [&](short8 (&kc)[4], short8 (&vc)[4],
                     short8 (&kn)[4], short8 (&vn)[4], int step, int sub) {
    __syncthreads();                 // prev buffer consumers done
    storeK(kc);
    storeV(vc, sub);
    if (step < 64) {                 // issue next-step loads; fly under compute
      loadK(kn, ksrc2); ksrc2 += 8192;
      loadV(vn);
    }
    __syncthreads();                 // LDS visible
    p2_compute(step, sub);
  };

  // ---------------- pass 1: stats (K prefetched one step ahead) ----------
  loadK(kA, ksrc); ksrc += 8192;     // step 0
  for (int s = 0; s < 64; s += 2) {
    __syncthreads();
    storeK(kA);
    loadK(kB, ksrc); ksrc += 8192;   // step s+1
    __syncthreads();
    p1_compute(s);

    __syncthreads();
    storeK(kB);
    loadK(kA, ksrc); ksrc += 8192;   // step s+2 (s=62 -> step 64, in bounds)
    __syncthreads();
    p1_compute(s + 1);
  }
  // tail step 64: data already in kA; prefetch pass-2 step 0 instead.
  ksrc2 = Kb + ((size_t)(n * LP + (t >> 4))) * 512 + (t & 15) * 8;
  vsA   = VT + ((size_t)(n * 512 + t)) * LP;
  vsB   = VT + ((size_t)(n * 512 + t + 256)) * LP;
  __syncthreads();
  storeK(kA);
  loadK(kB, ksrc2); ksrc2 += 8192;   // pass-2 step 0 K
  loadV(vA);                         // pass-2 step 0 V
  __syncthreads();
  p1_compute(64);

  // cross-lane combine of (m, z); loads above fly under this too
  #pragma unroll
  for (int off = 1; off < 16; off <<= 1) {
    #pragma unroll
    for (int gg = 0; gg < 2; ++gg)
      #pragma unroll
      for (int r = 0; r < 4; ++r) {
        const float mo = __shfl_xor(m_[gg][r], off);
        const float zo = __shfl_xor(z_[gg][r], off);
        const float mn = fmaxf(m_[gg][r], mo);
        z_[gg][r] = z_[gg][r] * __expf(m_[gg][r] - mn) + zo * __expf(mo - mn);
        m_[gg][r] = mn;
      }
  }
  #pragma unroll
  for (int gg = 0; gg < 2; ++gg)
    #pragma unroll
    for (int r = 0; r < 4; ++r) zi[gg][r] = 1.0f / z_[gg][r];

  // ---------------- pass 2: P + AV (K and V prefetched) ------------------
  // pairing: pass-2 step 0 lives in (kB, vA); alternate from there.
  for (int pair = 0; pair < 32; ++pair) {
    p2_step(kB, vA, kA, vB, 2 * pair,     0);
    p2_step(kA, vB, kB, vA, 2 * pair + 1, 1);
    __syncthreads();                 // Ps + Vt complete for this pair
    mix_av();
  }
  p2_step(kB, vA, kA, vB, 64, 0);    // tail: zeros Ps half 1 in-compute
  __syncthreads();
  mix_av();

  #pragma unroll
  for (int gg = 0; gg < 2; ++gg)
    #pragma unroll
    for (int ch = 0; ch < 4; ++ch) {
      const int d = (w * 2 + gg) * 64 + ch * 16 + lm;
      #pragma unroll
      for (int r = 0; r < 4; ++r)
        aob[((size_t)(n * LQ + q0 + quad * 4 + r)) * 512 + d] = f2bf(o_[gg][ch][r]);
    }
}

// ---------------------------------------------------------------------------
// swiglu: h = silu(h1+b1)*(h2+b2), raw [8192][4096] bf16 -> padded bf16
// ---------------------------------------------------------------------------
__global__ __launch_bounds__(256) void swiglu_kernel(
    const ushort_t* __restrict__ hraw, const float* __restrict__ bias,
    ushort_t* __restrict__ hpad)
{
  const int tok = blockIdx.x;
  const int n = tok >> 10, l = tok & 1023;
  const size_t src = (size_t)tok * 4096;
  const size_t dst = ((size_t)n * 1026 + l + 1) * 2048;
  for (int c = threadIdx.x; c < 2048; c += 256) {
    float h1 = bf2f(hraw[src + c]) + bias[c];
    float h2 = bf2f(hraw[src + 2048 + c]) + bias[2048 + c];
    float s = h1 / (1.f + __expf(-h1));
    hpad[dst + c] = f2bf(s * h2);
  }
}

__global__ __launch_bounds__(256) void zero_pads_kernel(
    ushort_t* __restrict__ x1b, ushort_t* __restrict__ hpad)
{
  const int b = blockIdx.x;
  const int n = b >> 1, side = b & 1;
  const size_t r = (size_t)n * 1026 + side * 1025;
  ushort2 z; z.x = 0; z.y = 0;
  *(ushort2*)&x1b[r * 512 + threadIdx.x * 2] = z;
  #pragma unroll
  for (int i = 0; i < 4; ++i)
    *(ushort2*)&hpad[r * 2048 + (threadIdx.x + 256 * i) * 2] = z;
}

// ---------------------------------------------------------------------------
// LayerNorm (fp32) + optional bf16 padded copy
// ---------------------------------------------------------------------------
__global__ __launch_bounds__(256) void ln_kernel(
    const float* __restrict__ in, const float* __restrict__ res,
    const float* __restrict__ g, const float* __restrict__ b,
    float* __restrict__ outp, ushort_t* __restrict__ bfout)
{
  const int w = threadIdx.x >> 6, lane = threadIdx.x & 63;
  const int tok = blockIdx.x * 4 + w;
  const size_t base = (size_t)tok * CH;
  float4 v0 = *(const float4*)&in[base + (lane << 2)];
  float4 v1 = *(const float4*)&in[base + 256 + (lane << 2)];
  if (res != nullptr) {
    float4 r0 = *(const float4*)&res[base + (lane << 2)];
    float4 r1 = *(const float4*)&res[base + 256 + (lane << 2)];
    v0.x += r0.x; v0.y += r0.y; v0.z += r0.z; v0.w += r0.w;
    v1.x += r1.x; v1.y += r1.y; v1.z += r1.z; v1.w += r1.w;
  }
  float s = v0.x + v0.y + v0.z + v0.w + v1.x + v1.y + v1.z + v1.w;
  #pragma unroll
  for (int off = 32; off > 0; off >>= 1) s += __shfl_xor(s, off);
  const float mu = s * (1.f / 512.f);
  float d0 = v0.x - mu, d1 = v0.y - mu, d2 = v0.z - mu, d3 = v0.w - mu;
  float d4 = v1.x - mu, d5 = v1.y - mu, d6 = v1.z - mu, d7 = v1.w - mu;
  float vs = d0*d0 + d1*d1 + d2*d2 + d3*d3 + d4*d4 + d5*d5 + d6*d6 + d7*d7;
  #pragma unroll
  for (int off = 32; off > 0; off >>= 1) vs += __shfl_xor(vs, off);
  const float r = rsqrtf(vs * (1.f / 512.f) + 1e-5f);
  float4 ga = *(const float4*)&g[(lane << 2)];
  float4 gb = *(const float4*)&g[256 + (lane << 2)];
  float4 ba = *(const float4*)&b[(lane << 2)];
  float4 bb = *(const float4*)&b[256 + (lane << 2)];
  float4 o0, o1;
  o0.x = d0 * r * ga.x + ba.x; o0.y = d1 * r * ga.y + ba.y;
  o0.z = d2 * r * ga.z + ba.z; o0.w = d3 * r * ga.w + ba.w;
  o1.x = d4 * r * gb.x + bb.x; o1.y = d5 * r * gb.y + bb.y;
  o1.z = d6 * r * gb.z + bb.z; o1.w = d7 * r * gb.w + bb.w;
  *(float4*)&outp[base + (lane << 2)] = o0;
  *(float4*)&outp[base + 256 + (lane << 2)] = o1;
  if (bfout != nullptr) {
    const int n = tok >> 10, ll = tok & 1023;
    const size_t bb2 = ((size_t)n * 1026 + ll + 1) * 512;
    ushort4 u0 = make_ushort4(f2bf(o0.x), f2bf(o0.y), f2bf(o0.z), f2bf(o0.w));
    ushort4 u1 = make_ushort4(f2bf(o1.x), f2bf(o1.y), f2bf(o1.z), f2bf(o1.w));
    *(ushort4*)&bfout[bb2 + (lane << 2)] = u0;
    *(ushort4*)&bfout[bb2 + 256 + (lane << 2)] = u1;
  }
}

// ---------------------------------------------------------------------------
extern "C" void kernel_launch(void* const* d_in, const int* in_sizes, int n_in,
                              void* d_out, int out_size, void* d_ws, size_t ws_size,
                              hipStream_t stream)
{
  (void)in_sizes; (void)n_in; (void)out_size; (void)ws_size;
  const float* x      = (const float*)d_in[0];
  const float* Wq     = (const float*)d_in[1];
  const float* Wk     = (const float*)d_in[2];
  const float* Wv     = (const float*)d_in[3];
  const float* Wo     = (const float*)d_in[4];
  const float* bo     = (const float*)d_in[5];
  const float* th_pre = (const float*)d_in[6];
  const float* th_post= (const float*)d_in[7];
  const float* p_keys = (const float*)d_in[8];
  const float* p_vals = (const float*)d_in[9];
  const float* c1w    = (const float*)d_in[10];
  const float* c1b    = (const float*)d_in[11];
  const float* c2w    = (const float*)d_in[12];
  const float* c2b    = (const float*)d_in[13];
  const float* ln1g   = (const float*)d_in[14];
  const float* ln1b   = (const float*)d_in[15];
  const float* ln2g   = (const float*)d_in[16];
  const float* ln2b   = (const float*)d_in[17];

  float* ws  = (float*)d_ws;
  float* out = (float*)d_out;

  ushort_t* Qb   = (ushort_t*)(ws + O_QB);
  ushort_t* Kb   = (ushort_t*)(ws + O_KB);
  ushort_t* Vb   = (ushort_t*)(ws + O_VB);
  ushort_t* VT   = (ushort_t*)(ws + O_VT);
  ushort_t* aob  = (ushort_t*)(ws + O_AOB);
  float*    abf  = ws + O_AF;
  float*    fbf  = abf;
  ushort_t* x1b  = (ushort_t*)(ws + O_X1B);
  ushort_t* hpad = (ushort_t*)(ws + O_HPAD);
  ushort_t* hraw = (ushort_t*)ws;         // overlays dead attn buffers
  ushort_t* w1p  = (ushort_t*)(ws + O_W1);
  ushort_t* w2p  = (ushort_t*)(ws + O_W2);
  ushort_t* wop  = (ushort_t*)(ws + O_WO);

  pack_bf16_kernel<<<4096, 256, 0, stream>>>(c1w, w1p, 1536, 3, 9);
  pack_bf16_kernel<<<512,  256, 0, stream>>>(c2w, w2p, 6144, 3, 11);
  pack_bf16_kernel<<<512,  256, 0, stream>>>(Wo,  wop, 512,  1, 9);

  qkv_mfma<<<dim3(128, 3), 256, 0, stream>>>(x, Wq, Wk, Wv, Qb, Kb, Vb);
  persist_kernel<<<256, 256, 0, stream>>>(p_keys, p_vals, Kb, Vb);
  vtrans_kernel<<<dim3(65, 8), 256, 0, stream>>>(Vb, VT);

  attn_mfma<<<dim3(64, 8), 256, 0, stream>>>(Qb, Kb, VT, th_pre, th_post, aob);

  // Wo: M=8192 N=512 K=512, +bias +residual(x) -> abf fp32
  mfma_gemm<2><<<dim3(64, 4), 256, 0, stream>>>(
      aob, wop, 512, 1024 * 512, 512, 512, bo, x, abf, nullptr);

  ln_kernel<<<2048, 256, 0, stream>>>(abf, nullptr, ln1g, ln1b, out, x1b);
  zero_pads_kernel<<<16, 256, 0, stream>>>(x1b, hpad);

  // conv1: M=8192 N=4096 K=1536 -> hraw bf16
  mfma_gemm<0><<<dim3(64, 32), 256, 0, stream>>>(
      x1b, w1p, 1536, 1026 * 512, 512, 4096, nullptr, nullptr, nullptr, hraw);

  swiglu_kernel<<<8192, 256, 0, stream>>>(hraw, c1b, hpad);

  // conv2: M=8192 N=512 K=6144, +bias -> fbf fp32
  mfma_gemm<1><<<dim3(64, 4), 256, 0, stream>>>(
      hpad, w2p, 6144, 1026 * 2048, 2048, 512, c2b, nullptr, fbf, nullptr);

  ln_kernel<<<2048, 256, 0, stream>>>(fbf, out, ln2g, ln2b, out, nullptr);
}

// Round 3
// 636.064 us; speedup vs baseline: 1.0626x; 1.0325x over previous
//
#include <hip/hip_runtime.h>
#include <cstddef>
#include <cstdint>

#define NB   8
#define LQ   1024
#define CH   512
#define HHE  8
#define HDD  64
#define PPM  16
#define LP   1040     // L + P
#define HID  2048

typedef unsigned short ushort_t;
typedef __attribute__((ext_vector_type(8))) short short8;
typedef __attribute__((ext_vector_type(4))) float floatx4;

// ---- workspace layout (float element offsets) ----
static const size_t O_QB   = 0;          // Qb bf16   (2,097,152 fl)
static const size_t O_KB   = 2097152;    // Kb bf16   (2,129,920 fl)
static const size_t O_VB   = 4227072;    // Vb bf16   (2,129,920 fl)
static const size_t O_VT   = 6356992;    // VT bf16   (2,129,920 fl)
static const size_t O_AOB  = 8486912;    // aob bf16  (2,097,152 fl)
static const size_t O_AF   = 10584064;   // abf/fbf fp32 (4,194,304 fl)
// hraw bf16 overlays floats [0 .. 16,777,216) -- all of the above are dead then
static const size_t O_X1B  = 16777216;   // x1b padded bf16 (2,101,248 fl)
static const size_t O_HPAD = 18878464;   // hpad bf16 (8,404,992 fl)
static const size_t O_W1   = 27283456;   // w1 bf16   (3,145,728 fl)
static const size_t O_W2   = 30429184;   // w2 bf16   (1,572,864 fl)
static const size_t O_WO   = 32002048;   // wo bf16   (131,072 fl)
// total 32,133,120 floats = 128.5 MB

__device__ __forceinline__ ushort_t f2bf(float f) {
  uint32_t u = __float_as_uint(f);
  u += 0x7FFFu + ((u >> 16) & 1u);
  return (ushort_t)(u >> 16);
}
__device__ __forceinline__ float bf2f(ushort_t h) {
  return __uint_as_float(((uint32_t)h) << 16);
}

__device__ __forceinline__ void async16(ushort_t* lds, const ushort_t* g) {
  __builtin_amdgcn_global_load_lds(
      (const __attribute__((address_space(1))) void*)g,
      (__attribute__((address_space(3))) void*)lds, 16, 0, 0);
}

// ---------------------------------------------------------------------------
// weight pack to bf16 [oc][k], k = dl*IC + ic; src[oc*K + ic*KD + dl]
// ---------------------------------------------------------------------------
__global__ __launch_bounds__(256) void pack_bf16_kernel(
    const float* __restrict__ src, ushort_t* __restrict__ dst,
    int K, int KD, int icShift)
{
  const int oc = blockIdx.x;
  const int icMask = (1 << icShift) - 1;
  for (int k = threadIdx.x; k < K; k += 256) {
    int ic = k & icMask, dl = k >> icShift;
    dst[(size_t)oc * K + k] = f2bf(src[(size_t)oc * K + ic * KD + dl]);
  }
}

// ---------------------------------------------------------------------------
// Generic bf16 MFMA GEMM, 128x128 tile, BK=32, global_load_lds staging.
// ---------------------------------------------------------------------------
template<int EPI>
__global__ __launch_bounds__(256, 2) void mfma_gemm(
    const ushort_t* __restrict__ Ab, const ushort_t* __restrict__ Bb,
    int K, int BS, int P, int NOUT,
    const float* __restrict__ bias, const float* __restrict__ res,
    float* __restrict__ outf, ushort_t* __restrict__ outh)
{
  __shared__ ushort_t As[128 * 32];
  __shared__ ushort_t Bs[128 * 32];
  const int t = threadIdx.x;
  const int w = t >> 6, l = t & 63;
  const int m0 = blockIdx.x * 128, n0 = blockIdx.y * 128;

  const int sub = l >> 2;
  const int kc8 = (l & 3) * 8;
  const ushort_t* aptr[2];
  const ushort_t* bptr[2];
  #pragma unroll
  for (int c = 0; c < 2; ++c) {
    int arow = m0 + w * 32 + c * 16 + sub;
    aptr[c] = Ab + (size_t)(arow >> 10) * BS + (size_t)(arow & 1023) * P + kc8;
    int brow = n0 + w * 32 + c * 16 + sub;
    bptr[c] = Bb + (size_t)brow * K + kc8;
  }

  const int wm = w >> 1, wn = w & 1;
  const int lm = l & 15, q = l >> 4;
  floatx4 acc[4][4];
  #pragma unroll
  for (int i = 0; i < 4; ++i)
    #pragma unroll
    for (int j = 0; j < 4; ++j)
      acc[i][j] = (floatx4){0.f, 0.f, 0.f, 0.f};

  const int kIters = K >> 5;
  for (int kt = 0; kt < kIters; ++kt) {
    __syncthreads();
    async16(&As[w * 1024 +   0], aptr[0]);
    async16(&As[w * 1024 + 512], aptr[1]);
    async16(&Bs[w * 1024 +   0], bptr[0]);
    async16(&Bs[w * 1024 + 512], bptr[1]);
    aptr[0] += 32; aptr[1] += 32; bptr[0] += 32; bptr[1] += 32;
    __syncthreads();
    short8 af[4], bf[4];
    #pragma unroll
    for (int i = 0; i < 4; ++i)
      af[i] = *(const short8*)&As[(wm * 64 + i * 16 + lm) * 32 + q * 8];
    #pragma unroll
    for (int i = 0; i < 4; ++i)
      bf[i] = *(const short8*)&Bs[(wn * 64 + i * 16 + lm) * 32 + q * 8];
    #pragma unroll
    for (int i = 0; i < 4; ++i)
      #pragma unroll
      for (int j = 0; j < 4; ++j)
        acc[i][j] = __builtin_amdgcn_mfma_f32_16x16x32_bf16(af[i], bf[j], acc[i][j], 0, 0, 0);
  }

  #pragma unroll
  for (int i = 0; i < 4; ++i) {
    #pragma unroll
    for (int j = 0; j < 4; ++j) {
      const int mbase = m0 + wm * 64 + i * 16 + q * 4;
      const int n = n0 + wn * 64 + j * 16 + lm;
      #pragma unroll
      for (int r = 0; r < 4; ++r) {
        const int m = mbase + r;
        float v = acc[i][j][r];
        if (EPI == 0) {
          outh[(size_t)m * NOUT + n] = f2bf(v);
        } else if (EPI == 1) {
          outf[(size_t)m * NOUT + n] = v + bias[n];
        } else {
          outf[(size_t)m * NOUT + n] = v + bias[n] + res[(size_t)m * NOUT + n];
        }
      }
    }
  }
}

// ---------------------------------------------------------------------------
// QKV projection via MFMA. grid (128, 3): blockIdx.x = 64-token tile,
// blockIdx.y = matrix (0=Q,1=K,2=V). W (64x64) staged to LDS in fragment
// order; A-fragments read from global fp32, converted in-register.
// Per head h: q[t, h*64+d] = sum_e x[t, h*64+e] * W[d][e].
// ---------------------------------------------------------------------------
__global__ __launch_bounds__(256) void qkv_mfma(
    const float* __restrict__ x,
    const float* __restrict__ Wq, const float* __restrict__ Wk, const float* __restrict__ Wv,
    ushort_t* __restrict__ qo, ushort_t* __restrict__ ko, ushort_t* __restrict__ vo)
{
  __shared__ ushort_t Ws[8 * 512];   // frag (nt,s): [((nt*2+s)*64 + lane)*8 + j]
  const int mat = blockIdx.y;
  const float* __restrict__ W = (mat == 0) ? Wq : (mat == 1) ? Wk : Wv;
  const int t = threadIdx.x;

  // stage W: element (oc, ic) -> frag slot (nt=oc>>4, s=ic>>5), lane quad*16+lm
  for (int e = t; e < 4096; e += 256) {
    const int oc = e >> 6, ic = e & 63;
    const int nt = oc >> 4, lmm = oc & 15, s = ic >> 5, qd = (ic >> 3) & 3, j = ic & 7;
    Ws[(((nt * 2 + s) * 4 + qd) * 16 + lmm) * 8 + j] = f2bf(W[e]);
  }

  const int w = t >> 6, l = t & 63;
  const int lm = l & 15, quad = l >> 4;
  const int tok0 = blockIdx.x * 64 + w * 16;

  // A-fragments: token row = tok0+lm, k = h*64 + s*32 + quad*8 .. +8
  short8 af[16];
  {
    const float* xrow = x + (size_t)(tok0 + lm) * CH + quad * 8;
    #pragma unroll
    for (int h = 0; h < 8; ++h) {
      #pragma unroll
      for (int s = 0; s < 2; ++s) {
        const float4 a = *(const float4*)(xrow + h * 64 + s * 32);
        const float4 b = *(const float4*)(xrow + h * 64 + s * 32 + 4);
        short8 f;
        f[0] = (short)f2bf(a.x); f[1] = (short)f2bf(a.y);
        f[2] = (short)f2bf(a.z); f[3] = (short)f2bf(a.w);
        f[4] = (short)f2bf(b.x); f[5] = (short)f2bf(b.y);
        f[6] = (short)f2bf(b.z); f[7] = (short)f2bf(b.w);
        af[h * 2 + s] = f;
      }
    }
  }
  __syncthreads();

  short8 bfr[8];
  #pragma unroll
  for (int nt = 0; nt < 4; ++nt)
    #pragma unroll
    for (int s = 0; s < 2; ++s)
      bfr[nt * 2 + s] = *(const short8*)&Ws[((nt * 2 + s) * 64 + l) * 8];

  const int n = tok0 >> 10, lpos = tok0 & 1023;
  ushort_t* outp;
  size_t base;
  if (mat == 0) { base = ((size_t)n * LQ + lpos) * CH; outp = qo; }
  else          { base = ((size_t)n * LP + lpos) * CH; outp = (mat == 1) ? ko : vo; }

  #pragma unroll
  for (int h = 0; h < 8; ++h) {
    floatx4 acc[4];
    #pragma unroll
    for (int nt = 0; nt < 4; ++nt) acc[nt] = (floatx4){0.f, 0.f, 0.f, 0.f};
    #pragma unroll
    for (int nt = 0; nt < 4; ++nt)
      #pragma unroll
      for (int s = 0; s < 2; ++s)
        acc[nt] = __builtin_amdgcn_mfma_f32_16x16x32_bf16(
            af[h * 2 + s], bfr[nt * 2 + s], acc[nt], 0, 0, 0);
    // C/D: col = lane&15 (d within tile), row = quad*4 + r (token)
    #pragma unroll
    for (int nt = 0; nt < 4; ++nt)
      #pragma unroll
      for (int r = 0; r < 4; ++r)
        outp[base + (size_t)(quad * 4 + r) * CH + h * 64 + nt * 16 + lm] =
            f2bf(acc[nt][r]);
  }
}

__global__ __launch_bounds__(256) void persist_kernel(
    const float* __restrict__ pk, const float* __restrict__ pv,
    ushort_t* __restrict__ ko, ushort_t* __restrict__ vo)
{
  const int t = blockIdx.x * 256 + threadIdx.x;
  const int n = t >> 13, p = (t >> 9) & 15, c = t & 511, d = c & 63;
  const size_t o = ((size_t)n * LP + LQ + p) * CH + c;
  ko[o] = f2bf(pk[p * 64 + d]);
  vo[o] = f2bf(pv[p * 64 + d]);
}

// ---------------------------------------------------------------------------
// V transpose: Vb [n][k(1040)][512] -> VT [n][d(512)][1040]
// ---------------------------------------------------------------------------
__global__ __launch_bounds__(256) void vtrans_kernel(
    const ushort_t* __restrict__ Vb, ushort_t* __restrict__ VT)
{
  __shared__ ushort_t Ls[16 * 520];
  const int n = blockIdx.y, k0 = blockIdx.x * 16;
  const int t = threadIdx.x;
  const int r = t >> 4;
  {
    const ushort_t* src = Vb + ((size_t)(n * LP + k0 + r)) * 512 + (t & 15) * 8;
    ushort_t* dst = &Ls[r * 520 + (t & 15) * 8];
    #pragma unroll
    for (int it = 0; it < 4; ++it)
      *(short8*)(dst + it * 128) = *(const short8*)(src + it * 128);
  }
  __syncthreads();
  #pragma unroll
  for (int rep = 0; rep < 2; ++rep) {
    const int d = t + rep * 256;
    short8 v0, v1;
    #pragma unroll
    for (int j = 0; j < 8; ++j) {
      v0[j] = (short)Ls[j * 520 + d];
      v1[j] = (short)Ls[(8 + j) * 520 + d];
    }
    ushort_t* dst = VT + ((size_t)(n * 512 + d)) * LP + k0;
    *(short8*)(dst)     = v0;
    *(short8*)(dst + 8) = v1;
  }
}

// ---------------------------------------------------------------------------
// MFMA flash attention with talking heads + ALiBi.  v4:
//  - head-split QK^T: wave w computes only heads 2w,2w+1 (4 MFMAs per
//    2-step phase, vs 16/step replicated 4x in v2); K fragments loaded
//    DIRECTLY from global into registers (L2-resident), prefetched one
//    phase ahead. The Ks LDS tile and its conflicted reads are gone.
//  - waves exchange energies via LDS E[2][h][k16][q16 pad 20]. STRICT
//    phase discipline: each barrier-delimited phase writes one set of LDS
//    objects and reads a disjoint set; both E buffers are written in the
//    same phase and consumed in the next (no cross-phase pipelining).
// Math identical to v2 (same f32 ops, same order).
// ---------------------------------------------------------------------------
__global__ __launch_bounds__(256, 2) void attn_mfma(
    const ushort_t* __restrict__ Qb, const ushort_t* __restrict__ Kb,
    const ushort_t* __restrict__ VT,
    const float* __restrict__ thpre, const float* __restrict__ thpost,
    ushort_t* __restrict__ aob)
{
  __shared__ ushort_t Vt[512 * 40];            // V^T tile [d][k-pair 32], pad 8
  __shared__ float    Ps[8 * 16 * 36];         // P [g][q][k-pair 32], pad 4
  __shared__ __align__(16) float Eb[2][8 * 16 * 20];  // E [buf][h][k16][q pad 20]
  const int n = blockIdx.y, q0 = blockIdx.x * 16;
  const int t = threadIdx.x;
  const int w = t >> 6, l = t & 63;
  const int lm = l & 15, quad = l >> 4;
  const float invs = 0.044194173824159216f;    // 1/sqrt(512)

  // Q fragments for this wave's 2 heads only
  short8 qf[4];
  {
    const ushort_t* qrow = Qb + ((size_t)(n * LQ + q0 + lm)) * 512 + (w * 2) * 64 + quad * 8;
    qf[0] = *(const short8*)(qrow);
    qf[1] = *(const short8*)(qrow + 32);
    qf[2] = *(const short8*)(qrow + 64);
    qf[3] = *(const short8*)(qrow + 96);
  }

  float tps[2][8], psl[2], tpo[2][8];
  #pragma unroll
  for (int gg = 0; gg < 2; ++gg) {
    const int g = w * 2 + gg;
    float ps = 0.f;
    #pragma unroll
    for (int h = 0; h < 8; ++h) {
      float tv = thpre[g * 8 + h] * invs;
      tps[gg][h] = tv;
      ps += tv * (1.0f / (float)(2 << h));     // slope_h = 2^-(h+1)
      tpo[gg][h] = thpost[g * 8 + h];
    }
    psl[gg] = ps;
  }

  float m_[2][4], z_[2][4], zi[2][4];
  #pragma unroll
  for (int gg = 0; gg < 2; ++gg)
    #pragma unroll
    for (int r = 0; r < 4; ++r) { m_[gg][r] = -1e30f; z_[gg][r] = 0.f; }

  floatx4 o_[2][4];
  #pragma unroll
  for (int gg = 0; gg < 2; ++gg)
    #pragma unroll
    for (int ch = 0; ch < 4; ++ch) o_[gg][ch] = (floatx4){0.f, 0.f, 0.f, 0.f};

  // ---- global sources ----
  const ushort_t* kg  = Kb + ((size_t)(n * LP + lm)) * 512 + (w * 2) * 64 + quad * 8;
  const ushort_t* vgA = VT + ((size_t)(n * 512) + t) * LP;
  const ushort_t* vgB = VT + ((size_t)(n * 512) + t + 256) * LP;

  short8 kfE[4], kfO[4], vX[4], vY[4];

  auto loadKg = [&](short8 (&r)[4], int step) {
    const ushort_t* p = kg + (size_t)step * 8192;
    r[0] = *(const short8*)(p);
    r[1] = *(const short8*)(p + 32);
    r[2] = *(const short8*)(p + 64);
    r[3] = *(const short8*)(p + 96);
  };
  auto loadVg = [&](short8 (&r)[4], int off) {
    r[0] = *(const short8*)(vgA + off); r[1] = *(const short8*)(vgA + off + 8);
    r[2] = *(const short8*)(vgB + off); r[3] = *(const short8*)(vgB + off + 8);
  };
  auto storeV = [&](short8 (&r)[4], int sub) {
    ushort_t* d0 = &Vt[(size_t)t * 40 + sub * 16];
    ushort_t* d1 = &Vt[(size_t)(t + 256) * 40 + sub * 16];
    *(short8*)(d0)     = r[0]; *(short8*)(d0 + 8) = r[1];
    *(short8*)(d1)     = r[2]; *(short8*)(d1 + 8) = r[3];
  };

  // wave's 2-head QK^T -> E[buf][h][k=lm][q=quad*4+j]
  auto qktE = [&](short8 (&kf)[4], int buf) {
    #pragma unroll
    for (int hh = 0; hh < 2; ++hh) {
      floatx4 e = (floatx4){0.f, 0.f, 0.f, 0.f};
      e = __builtin_amdgcn_mfma_f32_16x16x32_bf16(qf[hh * 2 + 0], kf[hh * 2 + 0], e, 0, 0, 0);
      e = __builtin_amdgcn_mfma_f32_16x16x32_bf16(qf[hh * 2 + 1], kf[hh * 2 + 1], e, 0, 0, 0);
      *(floatx4*)&Eb[buf][(((w * 2 + hh) * 16 + lm)) * 20 + quad * 4] = e;
    }
  };

  auto mixP1 = [&](int step, int buf) {
    floatx4 e4[8];
    #pragma unroll
    for (int h = 0; h < 8; ++h)
      e4[h] = *(const floatx4*)&Eb[buf][(h * 16 + lm) * 20 + quad * 4];
    const int k0 = step * 16;
    const bool alibi = (step < 64);
    #pragma unroll
    for (int r = 0; r < 4; ++r) {
      const float dist = fabsf((float)(q0 + quad * 4 + r - (k0 + lm)));
      #pragma unroll
      for (int gg = 0; gg < 2; ++gg) {
        float s = tps[gg][0] * e4[0][r];
        #pragma unroll
        for (int h = 1; h < 8; ++h) s += tps[gg][h] * e4[h][r];
        if (alibi) s -= dist * psl[gg];
        const float mo = m_[gg][r];
        const float mn = fmaxf(mo, s);
        z_[gg][r] = z_[gg][r] * __expf(mo - mn) + __expf(s - mn);
        m_[gg][r] = mn;
      }
    }
  };

  auto pCompute = [&](int step, int sub, int buf) {
    floatx4 e4[8];
    #pragma unroll
    for (int h = 0; h < 8; ++h)
      e4[h] = *(const floatx4*)&Eb[buf][(h * 16 + lm) * 20 + quad * 4];
    const int k0 = step * 16;
    const bool alibi = (step < 64);
    #pragma unroll
    for (int r = 0; r < 4; ++r) {
      const float dist = fabsf((float)(q0 + quad * 4 + r - (k0 + lm)));
      #pragma unroll
      for (int gg = 0; gg < 2; ++gg) {
        float s = tps[gg][0] * e4[0][r];
        #pragma unroll
        for (int h = 1; h < 8; ++h) s += tps[gg][h] * e4[h][r];
        if (alibi) s -= dist * psl[gg];
        const float p = __expf(s - m_[gg][r]) * zi[gg][r];
        Ps[((w * 2 + gg) * 16 + quad * 4 + r) * 36 + sub * 16 + lm] = p;
        if (step == 64)
          Ps[((w * 2 + gg) * 16 + quad * 4 + r) * 36 + 16 + lm] = 0.f;
      }
    }
  };

  auto mix_av = [&]() {
    float pm[2][8];
    #pragma unroll
    for (int gg = 0; gg < 2; ++gg)
      #pragma unroll
      for (int j = 0; j < 8; ++j) pm[gg][j] = 0.f;
    #pragma unroll
    for (int g = 0; g < 8; ++g) {
      const float4 pa = *(const float4*)&Ps[(g * 16 + lm) * 36 + quad * 8];
      const float4 pb = *(const float4*)&Ps[(g * 16 + lm) * 36 + quad * 8 + 4];
      #pragma unroll
      for (int gg = 0; gg < 2; ++gg) {
        const float tw = tpo[gg][g];
        pm[gg][0] += tw * pa.x; pm[gg][1] += tw * pa.y;
        pm[gg][2] += tw * pa.z; pm[gg][3] += tw * pa.w;
        pm[gg][4] += tw * pb.x; pm[gg][5] += tw * pb.y;
        pm[gg][6] += tw * pb.z; pm[gg][7] += tw * pb.w;
      }
    }
    short8 pk[2];
    #pragma unroll
    for (int gg = 0; gg < 2; ++gg)
      #pragma unroll
      for (int j = 0; j < 8; ++j) pk[gg][j] = (short)f2bf(pm[gg][j]);
    #pragma unroll
    for (int gg = 0; gg < 2; ++gg) {
      #pragma unroll
      for (int ch = 0; ch < 4; ++ch) {
        const int d = (w * 2 + gg) * 64 + ch * 16 + lm;
        const short8 vf = *(const short8*)&Vt[d * 40 + quad * 8];
        o_[gg][ch] = __builtin_amdgcn_mfma_f32_16x16x32_bf16(pk[gg], vf, o_[gg][ch], 0, 0, 0);
      }
    }
  };

  // ---------------- pass 1: stats -----------------------------------------
  // Phase W(s): write E[0]<-step s, E[1]<-step s+1; prefetch K s+2,s+3.
  // barrier. Phase R(s): read E[0],E[1]. barrier.
  loadKg(kfE, 0);
  loadKg(kfO, 1);
  for (int s = 0; s < 64; s += 2) {
    qktE(kfE, 0);
    qktE(kfO, 1);
    loadKg(kfE, s + 2);                   // s=62 -> step 64 (in bounds)
    if (s + 3 <= 64) loadKg(kfO, s + 3);
    __syncthreads();                      // E ready
    mixP1(s, 0);
    mixP1(s + 1, 1);
    __syncthreads();                      // readers done before next E write
  }
  qktE(kfE, 0);                           // step 64
  __syncthreads();
  mixP1(64, 0);

  // prefetch pass-2 K pair 0 and V pair 0 (fly under the combine)
  loadKg(kfE, 0);
  loadKg(kfO, 1);
  loadVg(vX, 0);
  loadVg(vY, 16);

  // cross-lane combine of (m, z)
  #pragma unroll
  for (int off = 1; off < 16; off <<= 1) {
    #pragma unroll
    for (int gg = 0; gg < 2; ++gg)
      #pragma unroll
      for (int r = 0; r < 4; ++r) {
        const float mo = __shfl_xor(m_[gg][r], off);
        const float zo = __shfl_xor(z_[gg][r], off);
        const float mn = fmaxf(m_[gg][r], mo);
        z_[gg][r] = z_[gg][r] * __expf(m_[gg][r] - mn) + zo * __expf(mo - mn);
        m_[gg][r] = mn;
      }
  }
  #pragma unroll
  for (int gg = 0; gg < 2; ++gg)
    #pragma unroll
    for (int r = 0; r < 4; ++r) zi[gg][r] = 1.0f / z_[gg][r];

  __syncthreads();   // mixP1(64) readers done before pass-2 E writes

  // ---------------- pass 2: P + AV ----------------------------------------
  // Per pair p: phase1 writes E[0]<-2p, E[1]<-2p+1 (+K prefetch); barrier;
  // phase2 reads E, writes Ps both subs + Vt both subs (+V prefetch);
  // barrier; mix_av reads Ps+Vt (next writes guarded by phase1's barrier).
  for (int p = 0; p < 32; ++p) {
    qktE(kfE, 0);
    qktE(kfO, 1);
    loadKg(kfE, 2 * p + 2);               // p=31 -> step 64 (tail)
    if (p < 31) loadKg(kfO, 2 * p + 3);
    __syncthreads();                      // E ready; prev mix_av done
    pCompute(2 * p,     0, 0);
    pCompute(2 * p + 1, 1, 1);
    storeV(vX, 0);
    storeV(vY, 1);
    loadVg(vX, 32 * (p + 1));             // p=31 -> offset 1024 (step 64)
    if (p < 31) loadVg(vY, 32 * (p + 1) + 16);
    __syncthreads();                      // Ps/Vt ready; E readers done
    mix_av();
  }
  // tail: step 64 (kfE holds it; vX holds V offset 1024)
  qktE(kfE, 0);
  __syncthreads();                        // E ready; mix_av(pair 31) done
  pCompute(64, 0, 0);                     // writes Ps sub0, zeros sub1
  storeV(vX, 0);
  __syncthreads();
  mix_av();                               // sub1 contributions are 0

  #pragma unroll
  for (int gg = 0; gg < 2; ++gg)
    #pragma unroll
    for (int ch = 0; ch < 4; ++ch) {
      const int d = (w * 2 + gg) * 64 + ch * 16 + lm;
      #pragma unroll
      for (int r = 0; r < 4; ++r)
        aob[((size_t)(n * LQ + q0 + quad * 4 + r)) * 512 + d] = f2bf(o_[gg][ch][r]);
    }
}

// ---------------------------------------------------------------------------
// swiglu: h = silu(h1+b1)*(h2+b2), raw [8192][4096] bf16 -> padded bf16
// ---------------------------------------------------------------------------
__global__ __launch_bounds__(256) void swiglu_kernel(
    const ushort_t* __restrict__ hraw, const float* __restrict__ bias,
    ushort_t* __restrict__ hpad)
{
  const int tok = blockIdx.x;
  const int n = tok >> 10, l = tok & 1023;
  const size_t src = (size_t)tok * 4096;
  const size_t dst = ((size_t)n * 1026 + l + 1) * 2048;
  for (int c = threadIdx.x; c < 2048; c += 256) {
    float h1 = bf2f(hraw[src + c]) + bias[c];
    float h2 = bf2f(hraw[src + 2048 + c]) + bias[2048 + c];
    float s = h1 / (1.f + __expf(-h1));
    hpad[dst + c] = f2bf(s * h2);
  }
}

__global__ __launch_bounds__(256) void zero_pads_kernel(
    ushort_t* __restrict__ x1b, ushort_t* __restrict__ hpad)
{
  const int b = blockIdx.x;
  const int n = b >> 1, side = b & 1;
  const size_t r = (size_t)n * 1026 + side * 1025;
  ushort2 z; z.x = 0; z.y = 0;
  *(ushort2*)&x1b[r * 512 + threadIdx.x * 2] = z;
  #pragma unroll
  for (int i = 0; i < 4; ++i)
    *(ushort2*)&hpad[r * 2048 + (threadIdx.x + 256 * i) * 2] = z;
}

// ---------------------------------------------------------------------------
// LayerNorm (fp32) + optional bf16 padded copy
// ---------------------------------------------------------------------------
__global__ __launch_bounds__(256) void ln_kernel(
    const float* __restrict__ in, const float* __restrict__ res,
    const float* __restrict__ g, const float* __restrict__ b,
    float* __restrict__ outp, ushort_t* __restrict__ bfout)
{
  const int w = threadIdx.x >> 6, lane = threadIdx.x & 63;
  const int tok = blockIdx.x * 4 + w;
  const size_t base = (size_t)tok * CH;
  float4 v0 = *(const float4*)&in[base + (lane << 2)];
  float4 v1 = *(const float4*)&in[base + 256 + (lane << 2)];
  if (res != nullptr) {
    float4 r0 = *(const float4*)&res[base + (lane << 2)];
    float4 r1 = *(const float4*)&res[base + 256 + (lane << 2)];
    v0.x += r0.x; v0.y += r0.y; v0.z += r0.z; v0.w += r0.w;
    v1.x += r1.x; v1.y += r1.y; v1.z += r1.z; v1.w += r1.w;
  }
  float s = v0.x + v0.y + v0.z + v0.w + v1.x + v1.y + v1.z + v1.w;
  #pragma unroll
  for (int off = 32; off > 0; off >>= 1) s += __shfl_xor(s, off);
  const float mu = s * (1.f / 512.f);
  float d0 = v0.x - mu, d1 = v0.y - mu, d2 = v0.z - mu, d3 = v0.w - mu;
  float d4 = v1.x - mu, d5 = v1.y - mu, d6 = v1.z - mu, d7 = v1.w - mu;
  float vs = d0*d0 + d1*d1 + d2*d2 + d3*d3 + d4*d4 + d5*d5 + d6*d6 + d7*d7;
  #pragma unroll
  for (int off = 32; off > 0; off >>= 1) vs += __shfl_xor(vs, off);
  const float r = rsqrtf(vs * (1.f / 512.f) + 1e-5f);
  float4 ga = *(const float4*)&g[(lane << 2)];
  float4 gb = *(const float4*)&g[256 + (lane << 2)];
  float4 ba = *(const float4*)&b[(lane << 2)];
  float4 bb = *(const float4*)&b[256 + (lane << 2)];
  float4 o0, o1;
  o0.x = d0 * r * ga.x + ba.x; o0.y = d1 * r * ga.y + ba.y;
  o0.z = d2 * r * ga.z + ba.z; o0.w = d3 * r * ga.w + ba.w;
  o1.x = d4 * r * gb.x + bb.x; o1.y = d5 * r * gb.y + bb.y;
  o1.z = d6 * r * gb.z + bb.z; o1.w = d7 * r * gb.w + bb.w;
  *(float4*)&outp[base + (lane << 2)] = o0;
  *(float4*)&outp[base + 256 + (lane << 2)] = o1;
  if (bfout != nullptr) {
    const int n = tok >> 10, ll = tok & 1023;
    const size_t bb2 = ((size_t)n * 1026 + ll + 1) * 512;
    ushort4 u0 = make_ushort4(f2bf(o0.x), f2bf(o0.y), f2bf(o0.z), f2bf(o0.w));
    ushort4 u1 = make_ushort4(f2bf(o1.x), f2bf(o1.y), f2bf(o1.z), f2bf(o1.w));
    *(ushort4*)&bfout[bb2 + (lane << 2)] = u0;
    *(ushort4*)&bfout[bb2 + 256 + (lane << 2)] = u1;
  }
}

// ---------------------------------------------------------------------------
extern "C" void kernel_launch(void* const* d_in, const int* in_sizes, int n_in,
                              void* d_out, int out_size, void* d_ws, size_t ws_size,
                              hipStream_t stream)
{
  (void)in_sizes; (void)n_in; (void)out_size; (void)ws_size;
  const float* x      = (const float*)d_in[0];
  const float* Wq     = (const float*)d_in[1];
  const float* Wk     = (const float*)d_in[2];
  const float* Wv     = (const float*)d_in[3];
  const float* Wo     = (const float*)d_in[4];
  const float* bo     = (const float*)d_in[5];
  const float* th_pre = (const float*)d_in[6];
  const float* th_post= (const float*)d_in[7];
  const float* p_keys = (const float*)d_in[8];
  const float* p_vals = (const float*)d_in[9];
  const float* c1w    = (const float*)d_in[10];
  const float* c1b    = (const float*)d_in[11];
  const float* c2w    = (const float*)d_in[12];
  const float* c2b    = (const float*)d_in[13];
  const float* ln1g   = (const float*)d_in[14];
  const float* ln1b   = (const float*)d_in[15];
  const float* ln2g   = (const float*)d_in[16];
  const float* ln2b   = (const float*)d_in[17];

  float* ws  = (float*)d_ws;
  float* out = (float*)d_out;

  ushort_t* Qb   = (ushort_t*)(ws + O_QB);
  ushort_t* Kb   = (ushort_t*)(ws + O_KB);
  ushort_t* Vb   = (ushort_t*)(ws + O_VB);
  ushort_t* VT   = (ushort_t*)(ws + O_VT);
  ushort_t* aob  = (ushort_t*)(ws + O_AOB);
  float*    abf  = ws + O_AF;
  float*    fbf  = abf;
  ushort_t* x1b  = (ushort_t*)(ws + O_X1B);
  ushort_t* hpad = (ushort_t*)(ws + O_HPAD);
  ushort_t* hraw = (ushort_t*)ws;         // overlays dead attn buffers
  ushort_t* w1p  = (ushort_t*)(ws + O_W1);
  ushort_t* w2p  = (ushort_t*)(ws + O_W2);
  ushort_t* wop  = (ushort_t*)(ws + O_WO);

  pack_bf16_kernel<<<4096, 256, 0, stream>>>(c1w, w1p, 1536, 3, 9);
  pack_bf16_kernel<<<512,  256, 0, stream>>>(c2w, w2p, 6144, 3, 11);
  pack_bf16_kernel<<<512,  256, 0, stream>>>(Wo,  wop, 512,  1, 9);

  qkv_mfma<<<dim3(128, 3), 256, 0, stream>>>(x, Wq, Wk, Wv, Qb, Kb, Vb);
  persist_kernel<<<256, 256, 0, stream>>>(p_keys, p_vals, Kb, Vb);
  vtrans_kernel<<<dim3(65, 8), 256, 0, stream>>>(Vb, VT);

  attn_mfma<<<dim3(64, 8), 256, 0, stream>>>(Qb, Kb, VT, th_pre, th_post, aob);

  // Wo: M=8192 N=512 K=512, +bias +residual(x) -> abf fp32
  mfma_gemm<2><<<dim3(64, 4), 256, 0, stream>>>(
      aob, wop, 512, 1024 * 512, 512, 512, bo, x, abf, nullptr);

  ln_kernel<<<2048, 256, 0, stream>>>(abf, nullptr, ln1g, ln1b, out, x1b);
  zero_pads_kernel<<<16, 256, 0, stream>>>(x1b, hpad);

  // conv1: M=8192 N=4096 K=1536 -> hraw bf16
  mfma_gemm<0><<<dim3(64, 32), 256, 0, stream>>>(
      x1b, w1p, 1536, 1026 * 512, 512, 4096, nullptr, nullptr, nullptr, hraw);

  swiglu_kernel<<<8192, 256, 0, stream>>>(hraw, c1b, hpad);

  // conv2: M=8192 N=512 K=6144, +bias -> fbf fp32
  mfma_gemm<1><<<dim3(64, 4), 256, 0, stream>>>(
      hpad, w2p, 6144, 1026 * 2048, 2048, 512, c2b, nullptr, fbf, nullptr);

  ln_kernel<<<2048, 256, 0, stream>>>(fbf, out, ln2g, ln2b, out, nullptr);
}

// Round 4
// 567.016 us; speedup vs baseline: 1.1920x; 1.1218x over previous
//
#include <hip/hip_runtime.h>
#include <cstddef>
#include <cstdint>

#define NB   8
#define LQ   1024
#define CH   512
#define HHE  8
#define HDD  64
#define PPM  16
#define LP   1040     // L + P
#define HID  2048

typedef unsigned short ushort_t;
typedef __attribute__((ext_vector_type(8))) short short8;
typedef __attribute__((ext_vector_type(4))) float floatx4;

// ---- workspace layout (float element offsets) ----
static const size_t O_QB   = 0;          // Qb bf16   (2,097,152 fl)
static const size_t O_KB   = 2097152;    // Kb bf16   (2,129,920 fl)
static const size_t O_VB   = 4227072;    // Vb bf16   (2,129,920 fl)
static const size_t O_VT   = 6356992;    // VT bf16   (2,129,920 fl)
static const size_t O_AOB  = 8486912;    // aob bf16  (2,097,152 fl)
static const size_t O_AF   = 10584064;   // abf/fbf fp32 (4,194,304 fl)
// hraw bf16 overlays floats [0 .. 16,777,216) -- all of the above are dead then
static const size_t O_X1B  = 16777216;   // x1b padded bf16 (2,101,248 fl)
static const size_t O_HPAD = 18878464;   // hpad bf16 (8,404,992 fl)
static const size_t O_W1   = 27283456;   // w1 bf16   (3,145,728 fl)
static const size_t O_W2   = 30429184;   // w2 bf16   (1,572,864 fl)
static const size_t O_WO   = 32002048;   // wo bf16   (131,072 fl)
// total 32,133,120 floats = 128.5 MB

__device__ __forceinline__ ushort_t f2bf(float f) {
  uint32_t u = __float_as_uint(f);
  u += 0x7FFFu + ((u >> 16) & 1u);
  return (ushort_t)(u >> 16);
}
__device__ __forceinline__ float bf2f(ushort_t h) {
  return __uint_as_float(((uint32_t)h) << 16);
}

__device__ __forceinline__ void async16(ushort_t* lds, const ushort_t* g) {
  __builtin_amdgcn_global_load_lds(
      (const __attribute__((address_space(1))) void*)g,
      (__attribute__((address_space(3))) void*)lds, 16, 0, 0);
}

// ---------------------------------------------------------------------------
// weight pack to bf16 [oc][k], k = dl*IC + ic; src[oc*K + ic*KD + dl]
// ---------------------------------------------------------------------------
__global__ __launch_bounds__(256) void pack_bf16_kernel(
    const float* __restrict__ src, ushort_t* __restrict__ dst,
    int K, int KD, int icShift)
{
  const int oc = blockIdx.x;
  const int icMask = (1 << icShift) - 1;
  for (int k = threadIdx.x; k < K; k += 256) {
    int ic = k & icMask, dl = k >> icShift;
    dst[(size_t)oc * K + k] = f2bf(src[(size_t)oc * K + ic * KD + dl]);
  }
}

// ---------------------------------------------------------------------------
// Generic bf16 MFMA GEMM, 128x128 tile, BK=32, global_load_lds staging.
// ---------------------------------------------------------------------------
template<int EPI>
__global__ __launch_bounds__(256, 2) void mfma_gemm(
    const ushort_t* __restrict__ Ab, const ushort_t* __restrict__ Bb,
    int K, int BS, int P, int NOUT,
    const float* __restrict__ bias, const float* __restrict__ res,
    float* __restrict__ outf, ushort_t* __restrict__ outh)
{
  __shared__ ushort_t As[128 * 32];
  __shared__ ushort_t Bs[128 * 32];
  const int t = threadIdx.x;
  const int w = t >> 6, l = t & 63;
  const int m0 = blockIdx.x * 128, n0 = blockIdx.y * 128;

  const int sub = l >> 2;
  const int kc8 = (l & 3) * 8;
  const ushort_t* aptr[2];
  const ushort_t* bptr[2];
  #pragma unroll
  for (int c = 0; c < 2; ++c) {
    int arow = m0 + w * 32 + c * 16 + sub;
    aptr[c] = Ab + (size_t)(arow >> 10) * BS + (size_t)(arow & 1023) * P + kc8;
    int brow = n0 + w * 32 + c * 16 + sub;
    bptr[c] = Bb + (size_t)brow * K + kc8;
  }

  const int wm = w >> 1, wn = w & 1;
  const int lm = l & 15, q = l >> 4;
  floatx4 acc[4][4];
  #pragma unroll
  for (int i = 0; i < 4; ++i)
    #pragma unroll
    for (int j = 0; j < 4; ++j)
      acc[i][j] = (floatx4){0.f, 0.f, 0.f, 0.f};

  const int kIters = K >> 5;
  for (int kt = 0; kt < kIters; ++kt) {
    __syncthreads();
    async16(&As[w * 1024 +   0], aptr[0]);
    async16(&As[w * 1024 + 512], aptr[1]);
    async16(&Bs[w * 1024 +   0], bptr[0]);
    async16(&Bs[w * 1024 + 512], bptr[1]);
    aptr[0] += 32; aptr[1] += 32; bptr[0] += 32; bptr[1] += 32;
    __syncthreads();
    short8 af[4], bf[4];
    #pragma unroll
    for (int i = 0; i < 4; ++i)
      af[i] = *(const short8*)&As[(wm * 64 + i * 16 + lm) * 32 + q * 8];
    #pragma unroll
    for (int i = 0; i < 4; ++i)
      bf[i] = *(const short8*)&Bs[(wn * 64 + i * 16 + lm) * 32 + q * 8];
    #pragma unroll
    for (int i = 0; i < 4; ++i)
      #pragma unroll
      for (int j = 0; j < 4; ++j)
        acc[i][j] = __builtin_amdgcn_mfma_f32_16x16x32_bf16(af[i], bf[j], acc[i][j], 0, 0, 0);
  }

  #pragma unroll
  for (int i = 0; i < 4; ++i) {
    #pragma unroll
    for (int j = 0; j < 4; ++j) {
      const int mbase = m0 + wm * 64 + i * 16 + q * 4;
      const int n = n0 + wn * 64 + j * 16 + lm;
      #pragma unroll
      for (int r = 0; r < 4; ++r) {
        const int m = mbase + r;
        float v = acc[i][j][r];
        if (EPI == 0) {
          outh[(size_t)m * NOUT + n] = f2bf(v);
        } else if (EPI == 1) {
          outf[(size_t)m * NOUT + n] = v + bias[n];
        } else {
          outf[(size_t)m * NOUT + n] = v + bias[n] + res[(size_t)m * NOUT + n];
        }
      }
    }
  }
}

// ---------------------------------------------------------------------------
// QKV projection via MFMA. grid (128, 3): blockIdx.x = 64-token tile,
// blockIdx.y = matrix (0=Q,1=K,2=V). W (64x64) staged to LDS in fragment
// order; A-fragments read from global fp32, converted in-register.
// Per head h: q[t, h*64+d] = sum_e x[t, h*64+e] * W[d][e].
// ---------------------------------------------------------------------------
__global__ __launch_bounds__(256) void qkv_mfma(
    const float* __restrict__ x,
    const float* __restrict__ Wq, const float* __restrict__ Wk, const float* __restrict__ Wv,
    ushort_t* __restrict__ qo, ushort_t* __restrict__ ko, ushort_t* __restrict__ vo)
{
  __shared__ ushort_t Ws[8 * 512];   // frag (nt,s): [((nt*2+s)*64 + lane)*8 + j]
  const int mat = blockIdx.y;
  const float* __restrict__ W = (mat == 0) ? Wq : (mat == 1) ? Wk : Wv;
  const int t = threadIdx.x;

  // stage W: element (oc, ic) -> frag slot (nt=oc>>4, s=ic>>5), lane quad*16+lm
  for (int e = t; e < 4096; e += 256) {
    const int oc = e >> 6, ic = e & 63;
    const int nt = oc >> 4, lmm = oc & 15, s = ic >> 5, qd = (ic >> 3) & 3, j = ic & 7;
    Ws[(((nt * 2 + s) * 4 + qd) * 16 + lmm) * 8 + j] = f2bf(W[e]);
  }

  const int w = t >> 6, l = t & 63;
  const int lm = l & 15, quad = l >> 4;
  const int tok0 = blockIdx.x * 64 + w * 16;

  // A-fragments: token row = tok0+lm, k = h*64 + s*32 + quad*8 .. +8
  short8 af[16];
  {
    const float* xrow = x + (size_t)(tok0 + lm) * CH + quad * 8;
    #pragma unroll
    for (int h = 0; h < 8; ++h) {
      #pragma unroll
      for (int s = 0; s < 2; ++s) {
        const float4 a = *(const float4*)(xrow + h * 64 + s * 32);
        const float4 b = *(const float4*)(xrow + h * 64 + s * 32 + 4);
        short8 f;
        f[0] = (short)f2bf(a.x); f[1] = (short)f2bf(a.y);
        f[2] = (short)f2bf(a.z); f[3] = (short)f2bf(a.w);
        f[4] = (short)f2bf(b.x); f[5] = (short)f2bf(b.y);
        f[6] = (short)f2bf(b.z); f[7] = (short)f2bf(b.w);
        af[h * 2 + s] = f;
      }
    }
  }
  __syncthreads();

  short8 bfr[8];
  #pragma unroll
  for (int nt = 0; nt < 4; ++nt)
    #pragma unroll
    for (int s = 0; s < 2; ++s)
      bfr[nt * 2 + s] = *(const short8*)&Ws[((nt * 2 + s) * 64 + l) * 8];

  const int n = tok0 >> 10, lpos = tok0 & 1023;
  ushort_t* outp;
  size_t base;
  if (mat == 0) { base = ((size_t)n * LQ + lpos) * CH; outp = qo; }
  else          { base = ((size_t)n * LP + lpos) * CH; outp = (mat == 1) ? ko : vo; }

  #pragma unroll
  for (int h = 0; h < 8; ++h) {
    floatx4 acc[4];
    #pragma unroll
    for (int nt = 0; nt < 4; ++nt) acc[nt] = (floatx4){0.f, 0.f, 0.f, 0.f};
    #pragma unroll
    for (int nt = 0; nt < 4; ++nt)
      #pragma unroll
      for (int s = 0; s < 2; ++s)
        acc[nt] = __builtin_amdgcn_mfma_f32_16x16x32_bf16(
            af[h * 2 + s], bfr[nt * 2 + s], acc[nt], 0, 0, 0);
    // C/D: col = lane&15 (d within tile), row = quad*4 + r (token)
    #pragma unroll
    for (int nt = 0; nt < 4; ++nt)
      #pragma unroll
      for (int r = 0; r < 4; ++r)
        outp[base + (size_t)(quad * 4 + r) * CH + h * 64 + nt * 16 + lm] =
            f2bf(acc[nt][r]);
  }
}

__global__ __launch_bounds__(256) void persist_kernel(
    const float* __restrict__ pk, const float* __restrict__ pv,
    ushort_t* __restrict__ ko, ushort_t* __restrict__ vo)
{
  const int t = blockIdx.x * 256 + threadIdx.x;
  const int n = t >> 13, p = (t >> 9) & 15, c = t & 511, d = c & 63;
  const size_t o = ((size_t)n * LP + LQ + p) * CH + c;
  ko[o] = f2bf(pk[p * 64 + d]);
  vo[o] = f2bf(pv[p * 64 + d]);
}

// ---------------------------------------------------------------------------
// V transpose: Vb [n][k(1040)][512] -> VT [n][d(512)][1040]
// ---------------------------------------------------------------------------
__global__ __launch_bounds__(256) void vtrans_kernel(
    const ushort_t* __restrict__ Vb, ushort_t* __restrict__ VT)
{
  __shared__ ushort_t Ls[16 * 520];
  const int n = blockIdx.y, k0 = blockIdx.x * 16;
  const int t = threadIdx.x;
  const int r = t >> 4;
  {
    const ushort_t* src = Vb + ((size_t)(n * LP + k0 + r)) * 512 + (t & 15) * 8;
    ushort_t* dst = &Ls[r * 520 + (t & 15) * 8];
    #pragma unroll
    for (int it = 0; it < 4; ++it)
      *(short8*)(dst + it * 128) = *(const short8*)(src + it * 128);
  }
  __syncthreads();
  #pragma unroll
  for (int rep = 0; rep < 2; ++rep) {
    const int d = t + rep * 256;
    short8 v0, v1;
    #pragma unroll
    for (int j = 0; j < 8; ++j) {
      v0[j] = (short)Ls[j * 520 + d];
      v1[j] = (short)Ls[(8 + j) * 520 + d];
    }
    ushort_t* dst = VT + ((size_t)(n * 512 + d)) * LP + k0;
    *(short8*)(dst)     = v0;
    *(short8*)(dst + 8) = v1;
  }
}

// ---------------------------------------------------------------------------
// MFMA flash attention with talking heads + ALiBi.  v5:
// SINGLE-PASS online softmax. Key identity: post-softmax talking heads is
// linear, so o_g = sum_h tpo[g,h] * (o_h / z_h) -- accumulate UNMIXED
// per-head outputs o_h online (per-head rescale well-defined), mix across
// heads ONCE at the end via an LDS exchange overlaid on dead Vt/Ps.
//  - wave w owns heads 2w, 2w+1 end-to-end (QK^T, softmax state, P·V).
//  - pre-softmax talking heads still needs the all-head energy exchange
//    (E tiles in LDS), as in v4.
//  - strict v4 phase discipline per pair: [W: write E | barrier |
//    R: read E, softmax-update, write Ps+Vt | barrier | PV: read Ps+Vt].
// ---------------------------------------------------------------------------
__global__ __launch_bounds__(256, 2) void attn_mfma(
    const ushort_t* __restrict__ Qb, const ushort_t* __restrict__ Kb,
    const ushort_t* __restrict__ VT,
    const float* __restrict__ thpre, const float* __restrict__ thpost,
    ushort_t* __restrict__ aob)
{
  // manual LDS layout so the final head-mix buffer can overlay Vt/Ps
  __shared__ __align__(16) char smem[79872];
  ushort_t* Vt  = (ushort_t*)smem;                    // [512][40] ush, 40960 B
  float*    Ps  = (float*)(smem + 40960);             // [8][16][36] fl, 18432 B
  float*    Eb0 = (float*)(smem + 59392);             // [8][16][20] fl, 10240 B
  float*    Eb1 = (float*)(smem + 69632);             // [8][16][20] fl, 10240 B
  float*    Ohn = (float*)smem;                       // [8][16][68] fl, 34816 B (overlay)

  const int n = blockIdx.y, q0 = blockIdx.x * 16;
  const int t = threadIdx.x;
  const int w = t >> 6, l = t & 63;
  const int lm = l & 15, quad = l >> 4;
  const float invs = 0.044194173824159216f;    // 1/sqrt(512)

  // Q fragments for this wave's 2 heads only
  short8 qf[4];
  {
    const ushort_t* qrow = Qb + ((size_t)(n * LQ + q0 + lm)) * 512 + (w * 2) * 64 + quad * 8;
    qf[0] = *(const short8*)(qrow);
    qf[1] = *(const short8*)(qrow + 32);
    qf[2] = *(const short8*)(qrow + 64);
    qf[3] = *(const short8*)(qrow + 96);
  }

  float tps[2][8], psl[2], tpo[2][8];
  #pragma unroll
  for (int gg = 0; gg < 2; ++gg) {
    const int g = w * 2 + gg;
    float ps = 0.f;
    #pragma unroll
    for (int h = 0; h < 8; ++h) {
      float tv = thpre[g * 8 + h] * invs;
      tps[gg][h] = tv;
      ps += tv * (1.0f / (float)(2 << h));     // slope_h = 2^-(h+1)
      tpo[gg][h] = thpost[g * 8 + h];
    }
    psl[gg] = ps;
  }

  float m_[2][4], z_[2][4];
  #pragma unroll
  for (int gg = 0; gg < 2; ++gg)
    #pragma unroll
    for (int r = 0; r < 4; ++r) { m_[gg][r] = -1e30f; z_[gg][r] = 0.f; }

  floatx4 o_[2][4];
  #pragma unroll
  for (int gg = 0; gg < 2; ++gg)
    #pragma unroll
    for (int ch = 0; ch < 4; ++ch) o_[gg][ch] = (floatx4){0.f, 0.f, 0.f, 0.f};

  // ---- global sources ----
  const ushort_t* kg  = Kb + ((size_t)(n * LP + lm)) * 512 + (w * 2) * 64 + quad * 8;
  const ushort_t* vgA = VT + ((size_t)(n * 512) + t) * LP;
  const ushort_t* vgB = VT + ((size_t)(n * 512) + t + 256) * LP;

  short8 kfE[4], kfO[4], vX[4], vY[4];

  auto loadKg = [&](short8 (&r)[4], int step) {
    const ushort_t* p = kg + (size_t)step * 8192;
    r[0] = *(const short8*)(p);
    r[1] = *(const short8*)(p + 32);
    r[2] = *(const short8*)(p + 64);
    r[3] = *(const short8*)(p + 96);
  };
  auto loadVg = [&](short8 (&r)[4], int off) {
    r[0] = *(const short8*)(vgA + off); r[1] = *(const short8*)(vgA + off + 8);
    r[2] = *(const short8*)(vgB + off); r[3] = *(const short8*)(vgB + off + 8);
  };
  auto storeV = [&](short8 (&r)[4], int sub) {
    ushort_t* d0 = &Vt[(size_t)t * 40 + sub * 16];
    ushort_t* d1 = &Vt[(size_t)(t + 256) * 40 + sub * 16];
    *(short8*)(d0)     = r[0]; *(short8*)(d0 + 8) = r[1];
    *(short8*)(d1)     = r[2]; *(short8*)(d1 + 8) = r[3];
  };

  // wave's 2-head QK^T -> E[buf][h][k=lm][q=quad*4+j]
  auto qktE = [&](short8 (&kf)[4], float* Eb) {
    #pragma unroll
    for (int hh = 0; hh < 2; ++hh) {
      floatx4 e = (floatx4){0.f, 0.f, 0.f, 0.f};
      e = __builtin_amdgcn_mfma_f32_16x16x32_bf16(qf[hh * 2 + 0], kf[hh * 2 + 0], e, 0, 0, 0);
      e = __builtin_amdgcn_mfma_f32_16x16x32_bf16(qf[hh * 2 + 1], kf[hh * 2 + 1], e, 0, 0, 0);
      *(floatx4*)&Eb[(((w * 2 + hh) * 16 + lm)) * 20 + quad * 4] = e;
    }
  };

  // online softmax update for one pair (steps 2p, 2p+1). Reads Eb0/Eb1,
  // rescales o_/z_, writes Ps (both subs).
  auto online2 = [&](int p) {
    float s0[2][4], s1[2][4];
    #pragma unroll
    for (int gg = 0; gg < 2; ++gg)
      #pragma unroll
      for (int r = 0; r < 4; ++r) { s0[gg][r] = 0.f; s1[gg][r] = 0.f; }
    #pragma unroll
    for (int h = 0; h < 8; ++h) {
      const floatx4 a = *(const floatx4*)&Eb0[(h * 16 + lm) * 20 + quad * 4];
      const floatx4 b = *(const floatx4*)&Eb1[(h * 16 + lm) * 20 + quad * 4];
      #pragma unroll
      for (int gg = 0; gg < 2; ++gg) {
        const float tv = tps[gg][h];
        #pragma unroll
        for (int r = 0; r < 4; ++r) {
          s0[gg][r] += tv * a[r];
          s1[gg][r] += tv * b[r];
        }
      }
    }
    const int k0 = 32 * p;
    float pm[2][4];
    #pragma unroll
    for (int r = 0; r < 4; ++r) {
      const float qpos = (float)(q0 + quad * 4 + r);
      const float d0 = fabsf(qpos - (float)(k0 + lm));
      const float d1 = fabsf(qpos - (float)(k0 + 16 + lm));
      #pragma unroll
      for (int gg = 0; gg < 2; ++gg) {
        s0[gg][r] -= d0 * psl[gg];
        s1[gg][r] -= d1 * psl[gg];
        pm[gg][r] = fmaxf(s0[gg][r], s1[gg][r]);
      }
    }
    #pragma unroll
    for (int off = 1; off < 16; off <<= 1)
      #pragma unroll
      for (int gg = 0; gg < 2; ++gg)
        #pragma unroll
        for (int r = 0; r < 4; ++r)
          pm[gg][r] = fmaxf(pm[gg][r], __shfl_xor(pm[gg][r], off));
    float sc[2][4];
    #pragma unroll
    for (int gg = 0; gg < 2; ++gg)
      #pragma unroll
      for (int r = 0; r < 4; ++r) {
        const float mn = fmaxf(m_[gg][r], pm[gg][r]);
        sc[gg][r] = __expf(m_[gg][r] - mn);
        const float p0 = __expf(s0[gg][r] - mn);
        const float p1 = __expf(s1[gg][r] - mn);
        z_[gg][r] = z_[gg][r] * sc[gg][r] + p0 + p1;
        m_[gg][r] = mn;
        float* prow = &Ps[((w * 2 + gg) * 16 + quad * 4 + r) * 36];
        prow[lm] = p0;
        prow[16 + lm] = p1;
      }
    #pragma unroll
    for (int gg = 0; gg < 2; ++gg)
      #pragma unroll
      for (int ch = 0; ch < 4; ++ch)
        #pragma unroll
        for (int r = 0; r < 4; ++r)
          o_[gg][ch][r] *= sc[gg][r];
  };

  // tail: single step 64 (persistent keys, no alibi)
  auto online1 = [&]() {
    float s0[2][4];
    #pragma unroll
    for (int gg = 0; gg < 2; ++gg)
      #pragma unroll
      for (int r = 0; r < 4; ++r) s0[gg][r] = 0.f;
    #pragma unroll
    for (int h = 0; h < 8; ++h) {
      const floatx4 a = *(const floatx4*)&Eb0[(h * 16 + lm) * 20 + quad * 4];
      #pragma unroll
      for (int gg = 0; gg < 2; ++gg) {
        const float tv = tps[gg][h];
        #pragma unroll
        for (int r = 0; r < 4; ++r) s0[gg][r] += tv * a[r];
      }
    }
    float pm[2][4];
    #pragma unroll
    for (int gg = 0; gg < 2; ++gg)
      #pragma unroll
      for (int r = 0; r < 4; ++r) pm[gg][r] = s0[gg][r];
    #pragma unroll
    for (int off = 1; off < 16; off <<= 1)
      #pragma unroll
      for (int gg = 0; gg < 2; ++gg)
        #pragma unroll
        for (int r = 0; r < 4; ++r)
          pm[gg][r] = fmaxf(pm[gg][r], __shfl_xor(pm[gg][r], off));
    float sc[2][4];
    #pragma unroll
    for (int gg = 0; gg < 2; ++gg)
      #pragma unroll
      for (int r = 0; r < 4; ++r) {
        const float mn = fmaxf(m_[gg][r], pm[gg][r]);
        sc[gg][r] = __expf(m_[gg][r] - mn);
        const float p0 = __expf(s0[gg][r] - mn);
        z_[gg][r] = z_[gg][r] * sc[gg][r] + p0;
        m_[gg][r] = mn;
        float* prow = &Ps[((w * 2 + gg) * 16 + quad * 4 + r) * 36];
        prow[lm] = p0;
        prow[16 + lm] = 0.f;
      }
    #pragma unroll
    for (int gg = 0; gg < 2; ++gg)
      #pragma unroll
      for (int ch = 0; ch < 4; ++ch)
        #pragma unroll
        for (int r = 0; r < 4; ++r)
          o_[gg][ch][r] *= sc[gg][r];
  };

  // P·V for own 2 heads: A-frag from Ps rows of head w*2+gg, B from Vt
  auto pv = [&]() {
    #pragma unroll
    for (int gg = 0; gg < 2; ++gg) {
      const float4 pa = *(const float4*)&Ps[((w * 2 + gg) * 16 + lm) * 36 + quad * 8];
      const float4 pb = *(const float4*)&Ps[((w * 2 + gg) * 16 + lm) * 36 + quad * 8 + 4];
      short8 pk;
      pk[0] = (short)f2bf(pa.x); pk[1] = (short)f2bf(pa.y);
      pk[2] = (short)f2bf(pa.z); pk[3] = (short)f2bf(pa.w);
      pk[4] = (short)f2bf(pb.x); pk[5] = (short)f2bf(pb.y);
      pk[6] = (short)f2bf(pb.z); pk[7] = (short)f2bf(pb.w);
      #pragma unroll
      for (int ch = 0; ch < 4; ++ch) {
        const int d = (w * 2 + gg) * 64 + ch * 16 + lm;
        const short8 vf = *(const short8*)&Vt[d * 40 + quad * 8];
        o_[gg][ch] = __builtin_amdgcn_mfma_f32_16x16x32_bf16(pk, vf, o_[gg][ch], 0, 0, 0);
      }
    }
  };

  // ---------------- single pass ------------------------------------------
  loadKg(kfE, 0);
  loadKg(kfO, 1);
  loadVg(vX, 0);
  loadVg(vY, 16);

  for (int p = 0; p < 32; ++p) {
    // W: write E (both bufs); prefetch next K pair
    qktE(kfE, Eb0);
    qktE(kfO, Eb1);
    loadKg(kfE, 2 * p + 2);               // p=31 -> step 64 (tail)
    if (p < 31) loadKg(kfO, 2 * p + 3);
    __syncthreads();                      // E ready; prev pv() done
    // R: read E, online update, write Ps + Vt; prefetch next V pair
    online2(p);
    storeV(vX, 0);
    storeV(vY, 1);
    loadVg(vX, 32 * (p + 1));             // p=31 -> offset 1024 (tail)
    if (p < 31) loadVg(vY, 32 * (p + 1) + 16);
    __syncthreads();                      // Ps/Vt ready; E readers done
    // PV: read Ps (own heads) + Vt, accumulate into o_
    pv();
  }
  // tail: step 64 (kfE holds it; vX holds V offset 1024)
  qktE(kfE, Eb0);
  __syncthreads();                        // E ready; pv(pair 31) done
  online1();
  storeV(vX, 0);
  __syncthreads();
  pv();                                   // sub1 P == 0 -> no contribution

  // ---------------- epilogue: z combine, per-head normalize, head mix ----
  #pragma unroll
  for (int off = 1; off < 16; off <<= 1)
    #pragma unroll
    for (int gg = 0; gg < 2; ++gg)
      #pragma unroll
      for (int r = 0; r < 4; ++r)
        z_[gg][r] += __shfl_xor(z_[gg][r], off);
  #pragma unroll
  for (int gg = 0; gg < 2; ++gg)
    #pragma unroll
    for (int r = 0; r < 4; ++r) {
      const float zi = 1.0f / z_[gg][r];
      #pragma unroll
      for (int ch = 0; ch < 4; ++ch) o_[gg][ch][r] *= zi;
    }

  __syncthreads();    // all pv() LDS reads done; safe to overlay Ohn
  #pragma unroll
  for (int gg = 0; gg < 2; ++gg)
    #pragma unroll
    for (int ch = 0; ch < 4; ++ch)
      #pragma unroll
      for (int r = 0; r < 4; ++r)
        Ohn[(w * 2 + gg) * 1088 + (quad * 4 + r) * 68 + ch * 16 + lm] = o_[gg][ch][r];
  __syncthreads();

  float acc[2][4][4];
  #pragma unroll
  for (int gg = 0; gg < 2; ++gg)
    #pragma unroll
    for (int ch = 0; ch < 4; ++ch)
      #pragma unroll
      for (int r = 0; r < 4; ++r) acc[gg][ch][r] = 0.f;
  #pragma unroll
  for (int h = 0; h < 8; ++h) {
    #pragma unroll
    for (int ch = 0; ch < 4; ++ch)
      #pragma unroll
      for (int r = 0; r < 4; ++r) {
        const float ov = Ohn[h * 1088 + (quad * 4 + r) * 68 + ch * 16 + lm];
        acc[0][ch][r] += tpo[0][h] * ov;
        acc[1][ch][r] += tpo[1][h] * ov;
      }
  }

  #pragma unroll
  for (int gg = 0; gg < 2; ++gg)
    #pragma unroll
    for (int ch = 0; ch < 4; ++ch) {
      const int d = (w * 2 + gg) * 64 + ch * 16 + lm;
      #pragma unroll
      for (int r = 0; r < 4; ++r)
        aob[((size_t)(n * LQ + q0 + quad * 4 + r)) * 512 + d] = f2bf(acc[gg][ch][r]);
    }
}

// ---------------------------------------------------------------------------
// swiglu: h = silu(h1+b1)*(h2+b2), raw [8192][4096] bf16 -> padded bf16
// ---------------------------------------------------------------------------
__global__ __launch_bounds__(256) void swiglu_kernel(
    const ushort_t* __restrict__ hraw, const float* __restrict__ bias,
    ushort_t* __restrict__ hpad)
{
  const int tok = blockIdx.x;
  const int n = tok >> 10, l = tok & 1023;
  const size_t src = (size_t)tok * 4096;
  const size_t dst = ((size_t)n * 1026 + l + 1) * 2048;
  for (int c = threadIdx.x; c < 2048; c += 256) {
    float h1 = bf2f(hraw[src + c]) + bias[c];
    float h2 = bf2f(hraw[src + 2048 + c]) + bias[2048 + c];
    float s = h1 / (1.f + __expf(-h1));
    hpad[dst + c] = f2bf(s * h2);
  }
}

__global__ __launch_bounds__(256) void zero_pads_kernel(
    ushort_t* __restrict__ x1b, ushort_t* __restrict__ hpad)
{
  const int b = blockIdx.x;
  const int n = b >> 1, side = b & 1;
  const size_t r = (size_t)n * 1026 + side * 1025;
  ushort2 z; z.x = 0; z.y = 0;
  *(ushort2*)&x1b[r * 512 + threadIdx.x * 2] = z;
  #pragma unroll
  for (int i = 0; i < 4; ++i)
    *(ushort2*)&hpad[r * 2048 + (threadIdx.x + 256 * i) * 2] = z;
}

// ---------------------------------------------------------------------------
// LayerNorm (fp32) + optional bf16 padded copy
// ---------------------------------------------------------------------------
__global__ __launch_bounds__(256) void ln_kernel(
    const float* __restrict__ in, const float* __restrict__ res,
    const float* __restrict__ g, const float* __restrict__ b,
    float* __restrict__ outp, ushort_t* __restrict__ bfout)
{
  const int w = threadIdx.x >> 6, lane = threadIdx.x & 63;
  const int tok = blockIdx.x * 4 + w;
  const size_t base = (size_t)tok * CH;
  float4 v0 = *(const float4*)&in[base + (lane << 2)];
  float4 v1 = *(const float4*)&in[base + 256 + (lane << 2)];
  if (res != nullptr) {
    float4 r0 = *(const float4*)&res[base + (lane << 2)];
    float4 r1 = *(const float4*)&res[base + 256 + (lane << 2)];
    v0.x += r0.x; v0.y += r0.y; v0.z += r0.z; v0.w += r0.w;
    v1.x += r1.x; v1.y += r1.y; v1.z += r1.z; v1.w += r1.w;
  }
  float s = v0.x + v0.y + v0.z + v0.w + v1.x + v1.y + v1.z + v1.w;
  #pragma unroll
  for (int off = 32; off > 0; off >>= 1) s += __shfl_xor(s, off);
  const float mu = s * (1.f / 512.f);
  float d0 = v0.x - mu, d1 = v0.y - mu, d2 = v0.z - mu, d3 = v0.w - mu;
  float d4 = v1.x - mu, d5 = v1.y - mu, d6 = v1.z - mu, d7 = v1.w - mu;
  float vs = d0*d0 + d1*d1 + d2*d2 + d3*d3 + d4*d4 + d5*d5 + d6*d6 + d7*d7;
  #pragma unroll
  for (int off = 32; off > 0; off >>= 1) vs += __shfl_xor(vs, off);
  const float r = rsqrtf(vs * (1.f / 512.f) + 1e-5f);
  float4 ga = *(const float4*)&g[(lane << 2)];
  float4 gb = *(const float4*)&g[256 + (lane << 2)];
  float4 ba = *(const float4*)&b[(lane << 2)];
  float4 bb = *(const float4*)&b[256 + (lane << 2)];
  float4 o0, o1;
  o0.x = d0 * r * ga.x + ba.x; o0.y = d1 * r * ga.y + ba.y;
  o0.z = d2 * r * ga.z + ba.z; o0.w = d3 * r * ga.w + ba.w;
  o1.x = d4 * r * gb.x + bb.x; o1.y = d5 * r * gb.y + bb.y;
  o1.z = d6 * r * gb.z + bb.z; o1.w = d7 * r * gb.w + bb.w;
  *(float4*)&outp[base + (lane << 2)] = o0;
  *(float4*)&outp[base + 256 + (lane << 2)] = o1;
  if (bfout != nullptr) {
    const int n = tok >> 10, ll = tok & 1023;
    const size_t bb2 = ((size_t)n * 1026 + ll + 1) * 512;
    ushort4 u0 = make_ushort4(f2bf(o0.x), f2bf(o0.y), f2bf(o0.z), f2bf(o0.w));
    ushort4 u1 = make_ushort4(f2bf(o1.x), f2bf(o1.y), f2bf(o1.z), f2bf(o1.w));
    *(ushort4*)&bfout[bb2 + (lane << 2)] = u0;
    *(ushort4*)&bfout[bb2 + 256 + (lane << 2)] = u1;
  }
}

// ---------------------------------------------------------------------------
extern "C" void kernel_launch(void* const* d_in, const int* in_sizes, int n_in,
                              void* d_out, int out_size, void* d_ws, size_t ws_size,
                              hipStream_t stream)
{
  (void)in_sizes; (void)n_in; (void)out_size; (void)ws_size;
  const float* x      = (const float*)d_in[0];
  const float* Wq     = (const float*)d_in[1];
  const float* Wk     = (const float*)d_in[2];
  const float* Wv     = (const float*)d_in[3];
  const float* Wo     = (const float*)d_in[4];
  const float* bo     = (const float*)d_in[5];
  const float* th_pre = (const float*)d_in[6];
  const float* th_post= (const float*)d_in[7];
  const float* p_keys = (const float*)d_in[8];
  const float* p_vals = (const float*)d_in[9];
  const float* c1w    = (const float*)d_in[10];
  const float* c1b    = (const float*)d_in[11];
  const float* c2w    = (const float*)d_in[12];
  const float* c2b    = (const float*)d_in[13];
  const float* ln1g   = (const float*)d_in[14];
  const float* ln1b   = (const float*)d_in[15];
  const float* ln2g   = (const float*)d_in[16];
  const float* ln2b   = (const float*)d_in[17];

  float* ws  = (float*)d_ws;
  float* out = (float*)d_out;

  ushort_t* Qb   = (ushort_t*)(ws + O_QB);
  ushort_t* Kb   = (ushort_t*)(ws + O_KB);
  ushort_t* Vb   = (ushort_t*)(ws + O_VB);
  ushort_t* VT   = (ushort_t*)(ws + O_VT);
  ushort_t* aob  = (ushort_t*)(ws + O_AOB);
  float*    abf  = ws + O_AF;
  float*    fbf  = abf;
  ushort_t* x1b  = (ushort_t*)(ws + O_X1B);
  ushort_t* hpad = (ushort_t*)(ws + O_HPAD);
  ushort_t* hraw = (ushort_t*)ws;         // overlays dead attn buffers
  ushort_t* w1p  = (ushort_t*)(ws + O_W1);
  ushort_t* w2p  = (ushort_t*)(ws + O_W2);
  ushort_t* wop  = (ushort_t*)(ws + O_WO);

  pack_bf16_kernel<<<4096, 256, 0, stream>>>(c1w, w1p, 1536, 3, 9);
  pack_bf16_kernel<<<512,  256, 0, stream>>>(c2w, w2p, 6144, 3, 11);
  pack_bf16_kernel<<<512,  256, 0, stream>>>(Wo,  wop, 512,  1, 9);

  qkv_mfma<<<dim3(128, 3), 256, 0, stream>>>(x, Wq, Wk, Wv, Qb, Kb, Vb);
  persist_kernel<<<256, 256, 0, stream>>>(p_keys, p_vals, Kb, Vb);
  vtrans_kernel<<<dim3(65, 8), 256, 0, stream>>>(Vb, VT);

  attn_mfma<<<dim3(64, 8), 256, 0, stream>>>(Qb, Kb, VT, th_pre, th_post, aob);

  // Wo: M=8192 N=512 K=512, +bias +residual(x) -> abf fp32
  mfma_gemm<2><<<dim3(64, 4), 256, 0, stream>>>(
      aob, wop, 512, 1024 * 512, 512, 512, bo, x, abf, nullptr);

  ln_kernel<<<2048, 256, 0, stream>>>(abf, nullptr, ln1g, ln1b, out, x1b);
  zero_pads_kernel<<<16, 256, 0, stream>>>(x1b, hpad);

  // conv1: M=8192 N=4096 K=1536 -> hraw bf16
  mfma_gemm<0><<<dim3(64, 32), 256, 0, stream>>>(
      x1b, w1p, 1536, 1026 * 512, 512, 4096, nullptr, nullptr, nullptr, hraw);

  swiglu_kernel<<<8192, 256, 0, stream>>>(hraw, c1b, hpad);

  // conv2: M=8192 N=512 K=6144, +bias -> fbf fp32
  mfma_gemm<1><<<dim3(64, 4), 256, 0, stream>>>(
      hpad, w2p, 6144, 1026 * 2048, 2048, 512, c2b, nullptr, fbf, nullptr);

  ln_kernel<<<2048, 256, 0, stream>>>(fbf, out, ln2g, ln2b, out, nullptr);
}